// Round 2
// baseline (10296.558 us; speedup 1.0000x reference)
//
#include <hip/hip_runtime.h>
#include <hip/hip_bf16.h>
#include <stdint.h>

typedef __bf16 bf16_t;
typedef __bf16 bf16x8 __attribute__((ext_vector_type(8)));
typedef float  f32x4  __attribute__((ext_vector_type(4)));

#define T_STEPS 512
#define BATCH   64
#define EMBD    512
#define HID     1024
#define G4      4096
#define MROWS   (T_STEPS * BATCH)   // 32768

// workspace layout (total ~33.8 MiB — small, to stay well inside ws_size)
#define OFF_CNT 0u           // barrier counters (root + 16 group lines)
#define OFF_H   8192u        // h double buffer: 2*64*1024 bf16 = 262144 B
#define OFF_E   270336u      // e bf16 [T*B][512] = 33,554,432 B

// ---------------- embedding gather: e[t*64+b][:] = bf16(emb[x[b][t]]) ----------------
__global__ __launch_bounds__(256) void k_gather(const int* __restrict__ x,
                                                const float* __restrict__ emb,
                                                bf16_t* __restrict__ e) {
  const int row  = blockIdx.x * 4 + (threadIdx.x >> 6);  // t*64+b
  const int lane = threadIdx.x & 63;
  const int t = row >> 6, b = row & 63;
  const int id = x[b * T_STEPS + t];
  const float* src = emb + (size_t)id * EMBD + lane * 8;
  float4 a = *(const float4*)src;
  float4 c = *(const float4*)(src + 4);
  bf16x8 o;
  o[0]=(bf16_t)a.x; o[1]=(bf16_t)a.y; o[2]=(bf16_t)a.z; o[3]=(bf16_t)a.w;
  o[4]=(bf16_t)c.x; o[5]=(bf16_t)c.y; o[6]=(bf16_t)c.z; o[7]=(bf16_t)c.w;
  *(bf16x8*)(e + (size_t)row * EMBD + lane * 8) = o;
}

// ---------------- persistent LSTM scan (xg GEMM fused per-step) ----------------
// 256 blocks x 256 threads. Block bb owns hidden units [bb*4, bb*4+4) -> 16 gate
// rows (row = q*1024 + bb*4 + du, q in {i,f,g,o}). W_hh/W_ih slices converted
// f32->bf16 into LDS at start (XOR-swizzled vs 16-way ds_read conflicts).
// Per step: acc = e[t] x Wi^T (16 MFMA) + h[t] x Ws^T (32 MFMA) + bias;
// gates -> c,h update; h double-buffered bf16 in ws; one 2-level device
// barrier per step with release/acquire fences (cross-XCD L2 non-coherence).
__global__ __launch_bounds__(256) void k_lstm(const float* __restrict__ Whh,
                                              const float* __restrict__ Wih,
                                              const float* __restrict__ bih,
                                              const float* __restrict__ bhh,
                                              const bf16_t* __restrict__ e,
                                              bf16_t* __restrict__ hbuf,
                                              int* __restrict__ cnt) {
  __shared__ __align__(16) char Ws[32768];   // [16][1024] bf16, swizzled
  __shared__ __align__(16) char Wi[16384];   // [16][512]  bf16, swizzled
  __shared__ float gbuf[64 * 17];
  __shared__ float bsh[16];
  const int tid = threadIdx.x;
  const int lane = tid & 63;
  const int w = tid >> 6;
  const int bb = blockIdx.x;
  const int l15 = lane & 15, lq = lane >> 4;
  const int nmask = (l15 & 7) << 4;

  // stage W_hh slice: 16 rows x 1024, f32 -> bf16
  for (int c0 = tid; c0 < 2048; c0 += 256) {
    int n = c0 >> 7, koff = c0 & 127;
    int grow = (n >> 2) * HID + bb * 4 + (n & 3);
    const float4* src = (const float4*)(Whh + (size_t)grow * HID + koff * 8);
    float4 a = src[0], b = src[1];
    bf16x8 v;
    v[0]=(bf16_t)a.x; v[1]=(bf16_t)a.y; v[2]=(bf16_t)a.z; v[3]=(bf16_t)a.w;
    v[4]=(bf16_t)b.x; v[5]=(bf16_t)b.y; v[6]=(bf16_t)b.z; v[7]=(bf16_t)b.w;
    *(bf16x8*)(Ws + n * 2048 + ((koff * 16) ^ ((n & 7) << 4))) = v;
  }
  // stage W_ih slice: 16 rows x 512, f32 -> bf16
  for (int c0 = tid; c0 < 1024; c0 += 256) {
    int n = c0 >> 6, koff = c0 & 63;
    int grow = (n >> 2) * HID + bb * 4 + (n & 3);
    const float4* src = (const float4*)(Wih + (size_t)grow * EMBD + koff * 8);
    float4 a = src[0], b = src[1];
    bf16x8 v;
    v[0]=(bf16_t)a.x; v[1]=(bf16_t)a.y; v[2]=(bf16_t)a.z; v[3]=(bf16_t)a.w;
    v[4]=(bf16_t)b.x; v[5]=(bf16_t)b.y; v[6]=(bf16_t)b.z; v[7]=(bf16_t)b.w;
    *(bf16x8*)(Wi + n * 1024 + ((koff * 16) ^ ((n & 7) << 4))) = v;
  }
  if (tid < 16) {
    int g = (tid >> 2) * HID + bb * 4 + (tid & 3);
    bsh[tid] = bih[g] + bhh[g];
  }
  __syncthreads();

  float c_reg = 0.f;
  const int u_du = tid & 3, u_b = tid >> 2;        // update mapping: 64 batches x 4 units
  const int a_row = w * 16 + l15;                  // batch row for A frags
  const char* wrow  = Ws + l15 * 2048;
  const char* wirow = Wi + l15 * 1024;

  for (int t = 0; t < T_STEPS; ++t) {
    const bf16_t* hp = hbuf + (size_t)(t & 1) * (BATCH * HID);
    bf16_t* hn = hbuf + (size_t)((t + 1) & 1) * (BATCH * HID);

    f32x4 acc0 = {0.f, 0.f, 0.f, 0.f};
    f32x4 acc1 = {0.f, 0.f, 0.f, 0.f};

    // xg part: e[t] [64][512] x Wi (h-independent)
    const bf16_t* ep = e + ((size_t)t * BATCH + a_row) * EMBD + lq * 8;
    #pragma unroll
    for (int kc = 0; kc < 16; kc += 2) {
      bf16x8 a0 = *(const bf16x8*)(ep + kc * 32);
      bf16x8 b0 = *(const bf16x8*)(wirow + ((kc * 64 + lq * 16) ^ nmask));
      bf16x8 a1 = *(const bf16x8*)(ep + (kc + 1) * 32);
      bf16x8 b1 = *(const bf16x8*)(wirow + (((kc + 1) * 64 + lq * 16) ^ nmask));
      acc0 = __builtin_amdgcn_mfma_f32_16x16x32_bf16(a0, b0, acc0, 0, 0, 0);
      acc1 = __builtin_amdgcn_mfma_f32_16x16x32_bf16(a1, b1, acc1, 0, 0, 0);
    }
    // recurrent part: h[t] [64][1024] x Ws
    const bf16_t* ap = hp + a_row * HID + lq * 8;
    #pragma unroll
    for (int kc = 0; kc < 32; kc += 2) {
      bf16x8 a0 = *(const bf16x8*)(ap + kc * 32);
      bf16x8 b0 = *(const bf16x8*)(wrow + ((kc * 64 + lq * 16) ^ nmask));
      bf16x8 a1 = *(const bf16x8*)(ap + (kc + 1) * 32);
      bf16x8 b1 = *(const bf16x8*)(wrow + (((kc + 1) * 64 + lq * 16) ^ nmask));
      acc0 = __builtin_amdgcn_mfma_f32_16x16x32_bf16(a0, b0, acc0, 0, 0, 0);
      acc1 = __builtin_amdgcn_mfma_f32_16x16x32_bf16(a1, b1, acc1, 0, 0, 0);
    }
    f32x4 acc = acc0 + acc1;
    #pragma unroll
    for (int r = 0; r < 4; ++r)
      gbuf[(w * 16 + lq * 4 + r) * 17 + l15] = acc[r] + bsh[l15];
    __syncthreads();
    {
      float gi = gbuf[u_b * 17 + u_du];
      float gf = gbuf[u_b * 17 + 4 + u_du];
      float gg = gbuf[u_b * 17 + 8 + u_du];
      float go = gbuf[u_b * 17 + 12 + u_du];
      float i_ = 1.f / (1.f + __expf(-gi));
      float f_ = 1.f / (1.f + __expf(-gf));
      float g_ = 1.f - 2.f / (1.f + __expf(2.f * gg));   // tanh
      float o_ = 1.f / (1.f + __expf(-go));
      c_reg = f_ * c_reg + i_ * g_;
      float hval = o_ * (1.f - 2.f / (1.f + __expf(2.f * c_reg)));
      hn[u_b * HID + bb * 4 + u_du] = (bf16_t)hval;
    }
    __syncthreads();
    if (tid == 0) {                                 // 2-level device barrier
      __threadfence();                              // release h writes
      int g = bb >> 4;
      int old = atomicAdd(cnt + (1 + g) * 64, 1);   // 16 group counters, own lines
      if (old == t * 16 + 15) atomicAdd(cnt, 1);    // last of group bumps root
      while (__hip_atomic_load(cnt, __ATOMIC_RELAXED, __HIP_MEMORY_SCOPE_AGENT) < (t + 1) * 16)
        __builtin_amdgcn_s_sleep(4);
      __threadfence();                              // acquire
    }
    __syncthreads();
  }
}

// ---------------- final FC: out[b][j] = h[b] . fc_w[j] + fc_b[j] ----------------
__global__ __launch_bounds__(256) void k_fc(const bf16_t* __restrict__ h,
                                            const float* __restrict__ fcw,
                                            const float* __restrict__ fcb,
                                            float* __restrict__ out) {
  __shared__ float hs[HID];
  const int b = blockIdx.x >> 2, js = blockIdx.x & 3;
  const int tid = threadIdx.x;
  #pragma unroll
  for (int i = 0; i < 4; ++i) hs[tid * 4 + i] = (float)h[b * HID + tid * 4 + i];
  __syncthreads();
  int j = js * 256 + tid;
  const float4* wr = (const float4*)(fcw + (size_t)j * HID);
  float s = 0.f;
  for (int k = 0; k < 256; ++k) {
    float4 wv = wr[k];
    s += hs[k * 4] * wv.x + hs[k * 4 + 1] * wv.y + hs[k * 4 + 2] * wv.z + hs[k * 4 + 3] * wv.w;
  }
  out[b * HID + j] = s + fcb[j];
}

extern "C" void kernel_launch(void* const* d_in, const int* in_sizes, int n_in,
                              void* d_out, int out_size, void* d_ws, size_t ws_size,
                              hipStream_t stream) {
  const int*   x   = (const int*)  d_in[0];
  const float* emb = (const float*)d_in[1];
  const float* Wih = (const float*)d_in[2];
  const float* bih = (const float*)d_in[3];
  const float* Whh = (const float*)d_in[4];
  const float* bhh = (const float*)d_in[5];
  const float* fcw = (const float*)d_in[6];
  const float* fcb = (const float*)d_in[7];
  float* out = (float*)d_out;

  char* ws = (char*)d_ws;
  int*    cnt  = (int*)   (ws + OFF_CNT);
  bf16_t* hbuf = (bf16_t*)(ws + OFF_H);
  bf16_t* e_b  = (bf16_t*)(ws + OFF_E);

  // zero barrier counters + both h buffers every call (graph-replay safe)
  hipMemsetAsync(ws, 0, OFF_H + 2 * BATCH * HID * sizeof(bf16_t), stream);

  k_gather<<<MROWS / 4, 256, 0, stream>>>(x, emb, e_b);
  k_lstm<<<256, 256, 0, stream>>>(Whh, Wih, bih, bhh, e_b, hbuf, cnt);
  k_fc<<<BATCH * 4, 256, 0, stream>>>(hbuf, fcw, fcb, out);
}

// Round 3
// 5695.801 us; speedup vs baseline: 1.8077x; 1.8077x over previous
//
#include <hip/hip_runtime.h>
#include <hip/hip_bf16.h>
#include <stdint.h>

typedef __bf16 bf16_t;
typedef __bf16 bf16x8 __attribute__((ext_vector_type(8)));
typedef float  f32x4  __attribute__((ext_vector_type(4)));

#define T_STEPS 512
#define BATCH   64
#define EMBD    512
#define HID     1024
#define MROWS   (T_STEPS * BATCH)   // 32768

// workspace layout (~33.8 MiB)
#define OFF_CNT 0u           // barrier counters (root + 16 group lines)
#define OFF_H   8192u        // h double buffer: 2*64*1024 bf16 = 262144 B
#define OFF_E   270336u      // e bf16 [T*B][512] = 33,554,432 B

// ---------------- embedding gather: e[t*64+b][:] = bf16(emb[x[b][t]]) ----------------
__global__ __launch_bounds__(256) void k_gather(const int* __restrict__ x,
                                                const float* __restrict__ emb,
                                                bf16_t* __restrict__ e) {
  const int row  = blockIdx.x * 4 + (threadIdx.x >> 6);  // t*64+b
  const int lane = threadIdx.x & 63;
  const int t = row >> 6, b = row & 63;
  const int id = x[b * T_STEPS + t];
  const float* src = emb + (size_t)id * EMBD + lane * 8;
  float4 a = *(const float4*)src;
  float4 c = *(const float4*)(src + 4);
  bf16x8 o;
  o[0]=(bf16_t)a.x; o[1]=(bf16_t)a.y; o[2]=(bf16_t)a.z; o[3]=(bf16_t)a.w;
  o[4]=(bf16_t)c.x; o[5]=(bf16_t)c.y; o[6]=(bf16_t)c.z; o[7]=(bf16_t)c.w;
  *(bf16x8*)(e + (size_t)row * EMBD + lane * 8) = o;
}

// ---------------- persistent LSTM scan ----------------
// 256 blocks x 512 threads. Block bb owns hidden units [bb*4, bb*4+4) -> 16 gate
// rows. W_hh/W_ih slices f32->bf16 in LDS (XOR-swizzled). K-split: waves 0-3 do
// e/h cols [0,512), waves 4-7 do [512,1024); partials reduced via LDS.
// h is exchanged via sc0sc1 (coherence-point) loads/stores — NO L2 invalidates,
// so e/W stay L2-cached. e-part computed before the barrier wait (overlap).
__global__ __launch_bounds__(512, 1) void k_lstm(const float* __restrict__ Whh,
                                                 const float* __restrict__ Wih,
                                                 const float* __restrict__ bih,
                                                 const float* __restrict__ bhh,
                                                 const bf16_t* __restrict__ e,
                                                 bf16_t* __restrict__ hbuf,
                                                 int* __restrict__ cnt) {
  __shared__ __align__(16) char Ws[32768];   // [16][1024] bf16, swizzled
  __shared__ __align__(16) char Wi[16384];   // [16][512]  bf16, swizzled
  __shared__ float gb[2][64 * 17];           // per-K-half gate partials
  __shared__ bf16_t hstage[256];
  __shared__ float bsh[16];
  const int tid = threadIdx.x;
  const int lane = tid & 63;
  const int w = tid >> 6;            // 0..7
  const int s = w >> 2;              // K-half
  const int w4 = w & 3;
  const int bb = blockIdx.x;
  const int l15 = lane & 15, lq = lane >> 4;
  const int nmask = (l15 & 7) << 4;

  // stage W_hh slice: 16 rows x 1024, f32 -> bf16, swizzled
  for (int c0 = tid; c0 < 2048; c0 += 512) {
    int n = c0 >> 7, koff = c0 & 127;
    int grow = (n >> 2) * HID + bb * 4 + (n & 3);
    const float4* src = (const float4*)(Whh + (size_t)grow * HID + koff * 8);
    float4 a = src[0], b = src[1];
    bf16x8 v;
    v[0]=(bf16_t)a.x; v[1]=(bf16_t)a.y; v[2]=(bf16_t)a.z; v[3]=(bf16_t)a.w;
    v[4]=(bf16_t)b.x; v[5]=(bf16_t)b.y; v[6]=(bf16_t)b.z; v[7]=(bf16_t)b.w;
    *(bf16x8*)(Ws + n * 2048 + ((koff * 16) ^ ((n & 7) << 4))) = v;
  }
  // stage W_ih slice: 16 rows x 512
  for (int c0 = tid; c0 < 1024; c0 += 512) {
    int n = c0 >> 6, koff = c0 & 63;
    int grow = (n >> 2) * HID + bb * 4 + (n & 3);
    const float4* src = (const float4*)(Wih + (size_t)grow * EMBD + koff * 8);
    float4 a = src[0], b = src[1];
    bf16x8 v;
    v[0]=(bf16_t)a.x; v[1]=(bf16_t)a.y; v[2]=(bf16_t)a.z; v[3]=(bf16_t)a.w;
    v[4]=(bf16_t)b.x; v[5]=(bf16_t)b.y; v[6]=(bf16_t)b.z; v[7]=(bf16_t)b.w;
    *(bf16x8*)(Wi + n * 1024 + ((koff * 16) ^ ((n & 7) << 4))) = v;
  }
  if (tid < 16) {
    int g = (tid >> 2) * HID + bb * 4 + (tid & 3);
    bsh[tid] = bih[g] + bhh[g];
  }
  __syncthreads();

  float c_reg = 0.f;
  const int u_b = tid >> 2, u_du = tid & 3;
  const int a_row = w4 * 16 + l15;
  const char* wrow  = Ws + l15 * 2048;
  const char* wirow = Wi + l15 * 1024;

  for (int t = 0; t < T_STEPS; ++t) {
    const bf16_t* hp = hbuf + (size_t)(t & 1) * (BATCH * HID);
    bf16_t* hn = hbuf + (size_t)((t + 1) & 1) * (BATCH * HID);

    f32x4 accA = {0.f, 0.f, 0.f, 0.f};
    f32x4 accB = {0.f, 0.f, 0.f, 0.f};

    // ---- e-part (h-independent; overlaps other blocks' tail + barrier) ----
    const bf16_t* ep = e + ((size_t)t * BATCH + a_row) * EMBD + s * 256 + lq * 8;
    #pragma unroll
    for (int kk = 0; kk < 8; ++kk) {
      bf16x8 a  = *(const bf16x8*)(ep + kk * 32);
      bf16x8 bf = *(const bf16x8*)(wirow + (((s * 8 + kk) * 64 + lq * 16) ^ nmask));
      if (kk & 1) accB = __builtin_amdgcn_mfma_f32_16x16x32_bf16(a, bf, accB, 0, 0, 0);
      else        accA = __builtin_amdgcn_mfma_f32_16x16x32_bf16(a, bf, accA, 0, 0, 0);
    }

    // ---- wait for h[t] ----
    if (t > 0) {
      if (tid == 0) {
        while (__hip_atomic_load(cnt, __ATOMIC_RELAXED, __HIP_MEMORY_SCOPE_AGENT) < t * 16)
          __builtin_amdgcn_s_sleep(1);
      }
      __syncthreads();
    }

    // ---- h-part: 16 coherent (sc0sc1) b128 loads, vmcnt-pipelined ----
    bf16x8 hv[16];
    const bf16_t* ap = hp + a_row * HID + s * 512 + lq * 8;
    #pragma unroll
    for (int kk = 0; kk < 16; ++kk)
      asm volatile("global_load_dwordx4 %0, %1, off offset:%2 sc0 sc1"
                   : "=v"(hv[kk]) : "v"(ap), "i"(kk * 64) : "memory");
    asm volatile("s_waitcnt vmcnt(8)" ::: "memory");
    __builtin_amdgcn_sched_barrier(0);
    #pragma unroll
    for (int kk = 0; kk < 8; ++kk) {
      bf16x8 bf = *(const bf16x8*)(wrow + (((s * 16 + kk) * 64 + lq * 16) ^ nmask));
      if (kk & 1) accB = __builtin_amdgcn_mfma_f32_16x16x32_bf16(hv[kk], bf, accB, 0, 0, 0);
      else        accA = __builtin_amdgcn_mfma_f32_16x16x32_bf16(hv[kk], bf, accA, 0, 0, 0);
    }
    asm volatile("s_waitcnt vmcnt(0)" ::: "memory");
    __builtin_amdgcn_sched_barrier(0);
    #pragma unroll
    for (int kk = 8; kk < 16; ++kk) {
      bf16x8 bf = *(const bf16x8*)(wrow + (((s * 16 + kk) * 64 + lq * 16) ^ nmask));
      if (kk & 1) accB = __builtin_amdgcn_mfma_f32_16x16x32_bf16(hv[kk], bf, accB, 0, 0, 0);
      else        accA = __builtin_amdgcn_mfma_f32_16x16x32_bf16(hv[kk], bf, accA, 0, 0, 0);
    }

    // ---- reduce partials ----
    f32x4 acc = accA + accB;
    #pragma unroll
    for (int r = 0; r < 4; ++r)
      gb[s][(w4 * 16 + lq * 4 + r) * 17 + l15] = acc[r];
    __syncthreads();

    // ---- gates + state update (threads 0..255: 64 batches x 4 units) ----
    if (tid < 256) {
      float gi = gb[0][u_b * 17 +      u_du] + gb[1][u_b * 17 +      u_du] + bsh[     u_du];
      float gf = gb[0][u_b * 17 +  4 + u_du] + gb[1][u_b * 17 +  4 + u_du] + bsh[ 4 + u_du];
      float gg = gb[0][u_b * 17 +  8 + u_du] + gb[1][u_b * 17 +  8 + u_du] + bsh[ 8 + u_du];
      float go = gb[0][u_b * 17 + 12 + u_du] + gb[1][u_b * 17 + 12 + u_du] + bsh[12 + u_du];
      float i_ = 1.f / (1.f + __expf(-gi));
      float f_ = 1.f / (1.f + __expf(-gf));
      float g_ = 1.f - 2.f / (1.f + __expf(2.f * gg));   // tanh
      float o_ = 1.f / (1.f + __expf(-go));
      c_reg = f_ * c_reg + i_ * g_;
      hstage[tid] = (bf16_t)(o_ * (1.f - 2.f / (1.f + __expf(2.f * c_reg))));
    }
    __syncthreads();

    // ---- wave 0: coherent 8B h-stores + release signal; others run ahead ----
    if (tid < 64) {
      uint2 val = *(const uint2*)(hstage + tid * 4);
      bf16_t* dst = hn + tid * HID + bb * 4;
      asm volatile("global_store_dwordx2 %0, %1, off sc0 sc1"
                   :: "v"(dst), "v"(val) : "memory");
    }
    if (tid == 0) {
      int g = bb >> 4;
      int old = __hip_atomic_fetch_add(cnt + (1 + g) * 64, 1,
                                       __ATOMIC_RELEASE, __HIP_MEMORY_SCOPE_AGENT);
      if (old == t * 16 + 15)
        __hip_atomic_fetch_add(cnt, 1, __ATOMIC_RELEASE, __HIP_MEMORY_SCOPE_AGENT);
    }
    // no trailing sync: waves run ahead into next e-part; next wait-sync rejoins
  }
}

// ---------------- final FC: out[b][j] = h[b] . fc_w[j] + fc_b[j] ----------------
__global__ __launch_bounds__(256) void k_fc(const bf16_t* __restrict__ h,
                                            const float* __restrict__ fcw,
                                            const float* __restrict__ fcb,
                                            float* __restrict__ out) {
  __shared__ float hs[HID];
  const int b = blockIdx.x >> 2, js = blockIdx.x & 3;
  const int tid = threadIdx.x;
  #pragma unroll
  for (int i = 0; i < 4; ++i) hs[tid * 4 + i] = (float)h[b * HID + tid * 4 + i];
  __syncthreads();
  int j = js * 256 + tid;
  const float4* wr = (const float4*)(fcw + (size_t)j * HID);
  float s = 0.f;
  for (int k = 0; k < 256; ++k) {
    float4 wv = wr[k];
    s += hs[k * 4] * wv.x + hs[k * 4 + 1] * wv.y + hs[k * 4 + 2] * wv.z + hs[k * 4 + 3] * wv.w;
  }
  out[b * HID + j] = s + fcb[j];
}

extern "C" void kernel_launch(void* const* d_in, const int* in_sizes, int n_in,
                              void* d_out, int out_size, void* d_ws, size_t ws_size,
                              hipStream_t stream) {
  const int*   x   = (const int*)  d_in[0];
  const float* emb = (const float*)d_in[1];
  const float* Wih = (const float*)d_in[2];
  const float* bih = (const float*)d_in[3];
  const float* Whh = (const float*)d_in[4];
  const float* bhh = (const float*)d_in[5];
  const float* fcw = (const float*)d_in[6];
  const float* fcb = (const float*)d_in[7];
  float* out = (float*)d_out;

  char* ws = (char*)d_ws;
  int*    cnt  = (int*)   (ws + OFF_CNT);
  bf16_t* hbuf = (bf16_t*)(ws + OFF_H);
  bf16_t* e_b  = (bf16_t*)(ws + OFF_E);

  // zero barrier counters + both h buffers every call (graph-replay safe)
  hipMemsetAsync(ws, 0, OFF_H + 2 * BATCH * HID * sizeof(bf16_t), stream);

  k_gather<<<MROWS / 4, 256, 0, stream>>>(x, emb, e_b);
  k_lstm<<<256, 512, 0, stream>>>(Whh, Wih, bih, bhh, e_b, hbuf, cnt);
  k_fc<<<BATCH * 4, 256, 0, stream>>>(hbuf, fcw, fcb, out);
}

// Round 4
// 5455.867 us; speedup vs baseline: 1.8872x; 1.0440x over previous
//
#include <hip/hip_runtime.h>
#include <hip/hip_bf16.h>
#include <stdint.h>

typedef __bf16 bf16_t;
typedef __bf16 bf16x8 __attribute__((ext_vector_type(8)));
typedef float  f32x4  __attribute__((ext_vector_type(4)));

#define T_STEPS 512
#define BATCH   64
#define EMBD    512
#define HID     1024
#define MROWS   (T_STEPS * BATCH)   // 32768
#define HSLOT   (BATCH * HID)       // 65536 elems = 131072 B per h slot

// ws layout (dynamic): [cnt 8KB][h ring slots*128KB][e 32MB]
#define OFF_CNT  0u
#define OFF_RING 8192u

// ---------------- embedding gather: e[t*64+b][:] = bf16(emb[x[b][t]]) ----------------
__global__ __launch_bounds__(256) void k_gather(const int* __restrict__ x,
                                                const float* __restrict__ emb,
                                                bf16_t* __restrict__ e) {
  const int row  = blockIdx.x * 4 + (threadIdx.x >> 6);  // t*64+b
  const int lane = threadIdx.x & 63;
  const int t = row >> 6, b = row & 63;
  const int id = x[b * T_STEPS + t];
  const float* src = emb + (size_t)id * EMBD + lane * 8;
  float4 a = *(const float4*)src;
  float4 c = *(const float4*)(src + 4);
  bf16x8 o;
  o[0]=(bf16_t)a.x; o[1]=(bf16_t)a.y; o[2]=(bf16_t)a.z; o[3]=(bf16_t)a.w;
  o[4]=(bf16_t)c.x; o[5]=(bf16_t)c.y; o[6]=(bf16_t)c.z; o[7]=(bf16_t)c.w;
  *(bf16x8*)(e + (size_t)row * EMBD + lane * 8) = o;
}

// ---------------- persistent LSTM scan ----------------
// 256 blocks x 512 threads; block bb owns hidden units [bb*4,bb*4+4) = 16 gate rows.
// COH=false (big ws): h in a 513-slot rotating ring — every address written once,
//   so NORMAL cached reads are race-free and h is fetched from L3 once per XCD
//   per step (L2-shared by its 32 blocks). COH=true: 2-slot ring + sc0sc1 reads.
// Signals: 16 group counters (no root), release-added by wave 0 after its
// write-through h store drains; ALL waves poll all 16 counters via __all.
// One __syncthreads per step; gb double-buffered by step parity so waves 1-7
// run ahead into e-part(t+1) while wave 0 updates gates/stores/signals.
template<bool COH>
__global__ __launch_bounds__(512, 1) void k_lstm(const float* __restrict__ Whh,
                                                 const float* __restrict__ Wih,
                                                 const float* __restrict__ bih,
                                                 const float* __restrict__ bhh,
                                                 const bf16_t* __restrict__ e,
                                                 bf16_t* __restrict__ ring,
                                                 int* __restrict__ cnt) {
  __shared__ __align__(16) char Ws[32768];   // [16][1024] bf16, XOR-swizzled
  __shared__ __align__(16) char Wi[16384];   // [16][512]  bf16, XOR-swizzled
  __shared__ float gb[2][2][64 * 17];        // [step parity][K-half][batch][16 gates]
  __shared__ float bsh[16];
  const int tid = threadIdx.x;
  const int lane = tid & 63;
  const int w = tid >> 6;            // 0..7
  const int s = w >> 2;              // K-half
  const int w4 = w & 3;
  const int bb = blockIdx.x;
  const int l15 = lane & 15, lq = lane >> 4;
  const int nmask = (l15 & 7) << 4;

  // stage W_hh slice: 16 rows x 1024, f32 -> bf16, swizzled
  for (int c0 = tid; c0 < 2048; c0 += 512) {
    int n = c0 >> 7, koff = c0 & 127;
    int grow = (n >> 2) * HID + bb * 4 + (n & 3);
    const float4* src = (const float4*)(Whh + (size_t)grow * HID + koff * 8);
    float4 a = src[0], b = src[1];
    bf16x8 v;
    v[0]=(bf16_t)a.x; v[1]=(bf16_t)a.y; v[2]=(bf16_t)a.z; v[3]=(bf16_t)a.w;
    v[4]=(bf16_t)b.x; v[5]=(bf16_t)b.y; v[6]=(bf16_t)b.z; v[7]=(bf16_t)b.w;
    *(bf16x8*)(Ws + n * 2048 + ((koff * 16) ^ ((n & 7) << 4))) = v;
  }
  // stage W_ih slice: 16 rows x 512
  for (int c0 = tid; c0 < 1024; c0 += 512) {
    int n = c0 >> 6, koff = c0 & 63;
    int grow = (n >> 2) * HID + bb * 4 + (n & 3);
    const float4* src = (const float4*)(Wih + (size_t)grow * EMBD + koff * 8);
    float4 a = src[0], b = src[1];
    bf16x8 v;
    v[0]=(bf16_t)a.x; v[1]=(bf16_t)a.y; v[2]=(bf16_t)a.z; v[3]=(bf16_t)a.w;
    v[4]=(bf16_t)b.x; v[5]=(bf16_t)b.y; v[6]=(bf16_t)b.z; v[7]=(bf16_t)b.w;
    *(bf16x8*)(Wi + n * 1024 + ((koff * 16) ^ ((n & 7) << 4))) = v;
  }
  if (tid < 16) {
    int g = (tid >> 2) * HID + bb * 4 + (tid & 3);
    bsh[tid] = bih[g] + bhh[g];
  }
  __syncthreads();

  float c_st[4] = {0.f, 0.f, 0.f, 0.f};      // wave-0 per-lane cell state (lane=batch)
  const int a_row = w4 * 16 + l15;
  const char* wrow  = Ws + l15 * 2048;
  const char* wirow = Wi + l15 * 1024;

  for (int t = 0; t < T_STEPS; ++t) {
    const bf16_t* hp = ring + (size_t)(COH ? (t & 1) : t) * HSLOT;
    bf16_t* hn = ring + (size_t)(COH ? ((t + 1) & 1) : (t + 1)) * HSLOT;

    f32x4 accA = {0.f, 0.f, 0.f, 0.f};
    f32x4 accB = {0.f, 0.f, 0.f, 0.f};

    // ---- e-part (h-independent; overlaps barrier/store latency) ----
    const bf16_t* ep = e + ((size_t)t * BATCH + a_row) * EMBD + s * 256 + lq * 8;
    #pragma unroll
    for (int kk = 0; kk < 8; ++kk) {
      bf16x8 a  = *(const bf16x8*)(ep + kk * 32);
      bf16x8 bf = *(const bf16x8*)(wirow + (((s * 8 + kk) * 64 + lq * 16) ^ nmask));
      if (kk & 1) accB = __builtin_amdgcn_mfma_f32_16x16x32_bf16(a, bf, accB, 0, 0, 0);
      else        accA = __builtin_amdgcn_mfma_f32_16x16x32_bf16(a, bf, accA, 0, 0, 0);
    }

    // ---- all waves: poll the 16 group counters for step t-1 completion ----
    if (t > 0) {
      const int target = t * 16;
      bool done;
      do {
        int cv = (lane < 16)
          ? __hip_atomic_load(cnt + (1 + lane) * 64, __ATOMIC_RELAXED, __HIP_MEMORY_SCOPE_AGENT)
          : 0x7fffffff;
        done = __all(cv >= target);
        if (!done) __builtin_amdgcn_s_sleep(2);
      } while (!done);
    }
    __builtin_amdgcn_sched_barrier(0);
    asm volatile("" ::: "memory");

    // ---- h-part: 16 b128 loads (normal cached in ring mode), vmcnt-pipelined ----
    bf16x8 hv[16];
    const bf16_t* ap = hp + a_row * HID + s * 512 + lq * 8;
    #pragma unroll
    for (int kk = 0; kk < 16; ++kk) {
      if constexpr (COH)
        asm volatile("global_load_dwordx4 %0, %1, off offset:%2 sc0 sc1"
                     : "=v"(hv[kk]) : "v"(ap), "i"(kk * 64) : "memory");
      else
        asm volatile("global_load_dwordx4 %0, %1, off offset:%2"
                     : "=v"(hv[kk]) : "v"(ap), "i"(kk * 64) : "memory");
    }
    asm volatile("s_waitcnt vmcnt(8)" ::: "memory");
    __builtin_amdgcn_sched_barrier(0);
    #pragma unroll
    for (int kk = 0; kk < 8; ++kk) {
      bf16x8 bf = *(const bf16x8*)(wrow + (((s * 16 + kk) * 64 + lq * 16) ^ nmask));
      if (kk & 1) accB = __builtin_amdgcn_mfma_f32_16x16x32_bf16(hv[kk], bf, accB, 0, 0, 0);
      else        accA = __builtin_amdgcn_mfma_f32_16x16x32_bf16(hv[kk], bf, accA, 0, 0, 0);
    }
    asm volatile("s_waitcnt vmcnt(0)" ::: "memory");
    __builtin_amdgcn_sched_barrier(0);
    #pragma unroll
    for (int kk = 8; kk < 16; ++kk) {
      bf16x8 bf = *(const bf16x8*)(wrow + (((s * 16 + kk) * 64 + lq * 16) ^ nmask));
      if (kk & 1) accB = __builtin_amdgcn_mfma_f32_16x16x32_bf16(hv[kk], bf, accB, 0, 0, 0);
      else        accA = __builtin_amdgcn_mfma_f32_16x16x32_bf16(hv[kk], bf, accA, 0, 0, 0);
    }

    // ---- publish partials (parity-buffered), one sync ----
    f32x4 acc = accA + accB;
    #pragma unroll
    for (int r = 0; r < 4; ++r)
      gb[t & 1][s][(w4 * 16 + lq * 4 + r) * 17 + l15] = acc[r];
    __syncthreads();

    // ---- wave 0 only: gates, state, write-through store, release signal ----
    if (w == 0) {
      const float* g0 = &gb[t & 1][0][lane * 17];
      const float* g1 = &gb[t & 1][1][lane * 17];
      union { bf16_t h4[4]; uint2 u2; } pk;
      #pragma unroll
      for (int du = 0; du < 4; ++du) {
        float gi = g0[du]      + g1[du]      + bsh[du];
        float gf = g0[4 + du]  + g1[4 + du]  + bsh[4 + du];
        float gg = g0[8 + du]  + g1[8 + du]  + bsh[8 + du];
        float go = g0[12 + du] + g1[12 + du] + bsh[12 + du];
        float i_ = 1.f / (1.f + __expf(-gi));
        float f_ = 1.f / (1.f + __expf(-gf));
        float g_ = 1.f - 2.f / (1.f + __expf(2.f * gg));   // tanh
        float o_ = 1.f / (1.f + __expf(-go));
        c_st[du] = f_ * c_st[du] + i_ * g_;
        pk.h4[du] = (bf16_t)(o_ * (1.f - 2.f / (1.f + __expf(2.f * c_st[du]))));
      }
      bf16_t* dst = hn + lane * HID + bb * 4;
      asm volatile("global_store_dwordx2 %0, %1, off sc0 sc1"
                   :: "v"(dst), "v"(pk.u2) : "memory");
      asm volatile("s_waitcnt vmcnt(0)" ::: "memory");
      if (lane == 0)
        __hip_atomic_fetch_add(cnt + (1 + (bb >> 4)) * 64, 1,
                               __ATOMIC_RELEASE, __HIP_MEMORY_SCOPE_AGENT);
    }
    // waves 1-7 run ahead into e-part(t+1); parity gb prevents the write race
  }
}

// ---------------- final FC: out[b][j] = h[b] . fc_w[j] + fc_b[j] ----------------
__global__ __launch_bounds__(256) void k_fc(const bf16_t* __restrict__ h,
                                            const float* __restrict__ fcw,
                                            const float* __restrict__ fcb,
                                            float* __restrict__ out) {
  __shared__ float hs[HID];
  const int b = blockIdx.x >> 2, js = blockIdx.x & 3;
  const int tid = threadIdx.x;
  #pragma unroll
  for (int i = 0; i < 4; ++i) hs[tid * 4 + i] = (float)h[b * HID + tid * 4 + i];
  __syncthreads();
  int j = js * 256 + tid;
  const float4* wr = (const float4*)(fcw + (size_t)j * HID);
  float s = 0.f;
  for (int k = 0; k < 256; ++k) {
    float4 wv = wr[k];
    s += hs[k * 4] * wv.x + hs[k * 4 + 1] * wv.y + hs[k * 4 + 2] * wv.z + hs[k * 4 + 3] * wv.w;
  }
  out[b * HID + j] = s + fcb[j];
}

extern "C" void kernel_launch(void* const* d_in, const int* in_sizes, int n_in,
                              void* d_out, int out_size, void* d_ws, size_t ws_size,
                              hipStream_t stream) {
  const int*   x   = (const int*)  d_in[0];
  const float* emb = (const float*)d_in[1];
  const float* Wih = (const float*)d_in[2];
  const float* bih = (const float*)d_in[3];
  const float* Whh = (const float*)d_in[4];
  const float* bhh = (const float*)d_in[5];
  const float* fcw = (const float*)d_in[6];
  const float* fcb = (const float*)d_in[7];
  float* out = (float*)d_out;

  const size_t slot_b = (size_t)HSLOT * sizeof(bf16_t);           // 128 KB
  const size_t need_big = OFF_RING + (size_t)(T_STEPS + 1) * slot_b + (size_t)MROWS * EMBD * sizeof(bf16_t);
  const bool big = ws_size >= need_big;                            // ~100.8 MB
  const int  slots = big ? (T_STEPS + 1) : 2;

  char* ws = (char*)d_ws;
  int*    cnt  = (int*)   (ws + OFF_CNT);
  bf16_t* ring = (bf16_t*)(ws + OFF_RING);
  bf16_t* e_b  = (bf16_t*)(ws + OFF_RING + (size_t)slots * slot_b);
  bf16_t* hfin = ring + (size_t)(big ? T_STEPS : (T_STEPS & 1)) * HSLOT;

  // zero counters + h slot 0 every call (graph-replay safe)
  hipMemsetAsync(ws, 0, OFF_RING + slot_b, stream);

  k_gather<<<MROWS / 4, 256, 0, stream>>>(x, emb, e_b);
  if (big) k_lstm<false><<<256, 512, 0, stream>>>(Whh, Wih, bih, bhh, e_b, ring, cnt);
  else     k_lstm<true ><<<256, 512, 0, stream>>>(Whh, Wih, bih, bhh, e_b, ring, cnt);
  k_fc<<<BATCH * 4, 256, 0, stream>>>(hfin, fcw, fcb, out);
}

// Round 6
// 3890.961 us; speedup vs baseline: 2.6463x; 1.4022x over previous
//
#include <hip/hip_runtime.h>
#include <hip/hip_bf16.h>
#include <stdint.h>

typedef __bf16 bf16_t;
typedef __bf16 bf16x8 __attribute__((ext_vector_type(8)));
typedef float  f32x4  __attribute__((ext_vector_type(4)));
typedef uint32_t u32x4 __attribute__((ext_vector_type(4)));

#define T_STEPS 512
#define BATCH   64
#define EMBD    512
#define HID     1024
#define MROWS   (T_STEPS * BATCH)   // 32768
#define HSLOT   (BATCH * HID)       // 65536 elems = 131072 B per h slot
#define NBLK    128                 // LSTM blocks; each owns 8 hidden units (32 gate rows)

// ws layout: [cnt 40KB][h ring slots*128KB][e 32MB]
#define OFF_CNT  0u
#define OFF_RING 40960u

// ---------------- embedding gather: e[t*64+b][:] = bf16(emb[x[b][t]]) ----------------
__global__ __launch_bounds__(256) void k_gather(const int* __restrict__ x,
                                                const float* __restrict__ emb,
                                                bf16_t* __restrict__ e) {
  const int row  = blockIdx.x * 4 + (threadIdx.x >> 6);  // t*64+b
  const int lane = threadIdx.x & 63;
  const int t = row >> 6, b = row & 63;
  const int id = x[b * T_STEPS + t];
  const float* src = emb + (size_t)id * EMBD + lane * 8;
  float4 a = *(const float4*)src;
  float4 c = *(const float4*)(src + 4);
  bf16x8 o;
  o[0]=(bf16_t)a.x; o[1]=(bf16_t)a.y; o[2]=(bf16_t)a.z; o[3]=(bf16_t)a.w;
  o[4]=(bf16_t)c.x; o[5]=(bf16_t)c.y; o[6]=(bf16_t)c.z; o[7]=(bf16_t)c.w;
  *(bf16x8*)(e + (size_t)row * EMBD + lane * 8) = o;
}

// ---------------- persistent LSTM scan ----------------
// 128 blocks x 512 threads. Block bb owns hidden units [bb*8,bb*8+8) = 32 gate
// rows (n = q*8+du). W_hh (64KB) + W_ih (32KB) slices f32->bf16 in LDS, XOR-
// swizzled. 8 waves = K-half s (2) x batch quarter w4 (4); each wave computes a
// [16 batch x 32 gate] C-tile (2 MFMA tiles) over its K-half.
// Signaling: 8 group counters on 4KB-spread cachelines; producers fire relaxed
// atomic adds after vmcnt(0)-drained write-through h stores; ONLY wave 0 polls
// (8 lanes, 1 load/iter), __syncthreads releases the block. 128 poller waves
// device-wide -> no L3 line queuing. h in write-once ring (normal cached
// loads) when ws permits, else 2-slot + sc0sc1 loads.
template<bool COH>
__global__ __launch_bounds__(512, 1) void k_lstm(const float* __restrict__ Whh,
                                                 const float* __restrict__ Wih,
                                                 const float* __restrict__ bih,
                                                 const float* __restrict__ bhh,
                                                 const bf16_t* __restrict__ e,
                                                 bf16_t* __restrict__ ring,
                                                 int* __restrict__ cnt) {
  __shared__ __align__(16) char Ws[65536];   // [32][1024] bf16, XOR-swizzled
  __shared__ __align__(16) char Wi[32768];   // [32][512]  bf16, XOR-swizzled
  __shared__ float gb[2][2][64 * 33];        // [parity][K-half][batch][32 gates]
  __shared__ float bsh[32];
  const int tid = threadIdx.x;
  const int lane = tid & 63;
  const int w = tid >> 6;            // 0..7
  const int s = w >> 2;              // K-half
  const int w4 = w & 3;              // batch quarter
  const int bb = blockIdx.x;
  const int l15 = lane & 15, lq = lane >> 4;
  const int nmask = (l15 & 7) << 4;

  // stage W_hh slice: 32 rows x 1024 f32 -> bf16 (4096 chunks of 8 floats)
  for (int c0 = tid; c0 < 4096; c0 += 512) {
    int n = c0 >> 7, koff = c0 & 127;
    int grow = (n >> 3) * HID + bb * 8 + (n & 7);
    const float4* src = (const float4*)(Whh + (size_t)grow * HID + koff * 8);
    float4 a = src[0], b = src[1];
    bf16x8 v;
    v[0]=(bf16_t)a.x; v[1]=(bf16_t)a.y; v[2]=(bf16_t)a.z; v[3]=(bf16_t)a.w;
    v[4]=(bf16_t)b.x; v[5]=(bf16_t)b.y; v[6]=(bf16_t)b.z; v[7]=(bf16_t)b.w;
    *(bf16x8*)(Ws + n * 2048 + ((koff * 16) ^ ((n & 7) << 4))) = v;
  }
  // stage W_ih slice: 32 rows x 512
  for (int c0 = tid; c0 < 2048; c0 += 512) {
    int n = c0 >> 6, koff = c0 & 63;
    int grow = (n >> 3) * HID + bb * 8 + (n & 7);
    const float4* src = (const float4*)(Wih + (size_t)grow * EMBD + koff * 8);
    float4 a = src[0], b = src[1];
    bf16x8 v;
    v[0]=(bf16_t)a.x; v[1]=(bf16_t)a.y; v[2]=(bf16_t)a.z; v[3]=(bf16_t)a.w;
    v[4]=(bf16_t)b.x; v[5]=(bf16_t)b.y; v[6]=(bf16_t)b.z; v[7]=(bf16_t)b.w;
    *(bf16x8*)(Wi + n * 1024 + ((koff * 16) ^ ((n & 7) << 4))) = v;
  }
  if (tid < 32) {
    int g = (tid >> 3) * HID + bb * 8 + (tid & 7);
    bsh[tid] = bih[g] + bhh[g];
  }
  __syncthreads();

  float c_st[8] = {0,0,0,0,0,0,0,0};   // wave-0: lane=batch, 8 hidden units
  const int a_row = w4 * 16 + l15;
  const char* wr0  = Ws + l15 * 2048;            // B-tile 0 rows
  const char* wr1  = Ws + (16 + l15) * 2048;     // B-tile 1 rows
  const char* wi0  = Wi + l15 * 1024;
  const char* wi1  = Wi + (16 + l15) * 1024;

  for (int t = 0; t < T_STEPS; ++t) {
    const bf16_t* hp = ring + (size_t)(COH ? (t & 1) : t) * HSLOT;
    bf16_t* hn = ring + (size_t)(COH ? ((t + 1) & 1) : (t + 1)) * HSLOT;
    const int par = t & 1;

    f32x4 acc0 = {0.f, 0.f, 0.f, 0.f};   // gate cols [0,16)
    f32x4 acc1 = {0.f, 0.f, 0.f, 0.f};   // gate cols [16,32)

    // ---- e-part (h-independent; overlaps store/signal latency) ----
    const bf16_t* ep = e + ((size_t)t * BATCH + a_row) * EMBD + s * 256 + lq * 8;
    #pragma unroll
    for (int kk = 0; kk < 8; ++kk) {
      bf16x8 a  = *(const bf16x8*)(ep + kk * 32);
      int off = ((s * 8 + kk) * 64 + lq * 16) ^ nmask;
      bf16x8 b0 = *(const bf16x8*)(wi0 + off);
      bf16x8 b1 = *(const bf16x8*)(wi1 + off);
      acc0 = __builtin_amdgcn_mfma_f32_16x16x32_bf16(a, b0, acc0, 0, 0, 0);
      acc1 = __builtin_amdgcn_mfma_f32_16x16x32_bf16(a, b1, acc1, 0, 0, 0);
    }

    // ---- wave 0 polls the 8 group counters for step t-1 completion ----
    if (w == 0 && t > 0) {
      const int target = t * 16;
      bool done;
      do {
        int cv = (lane < 8)
          ? __hip_atomic_load(cnt + (1 + lane) * 1024, __ATOMIC_RELAXED, __HIP_MEMORY_SCOPE_AGENT)
          : 0x7fffffff;
        done = __all(cv >= target);
        if (!done) __builtin_amdgcn_s_sleep(1);
      } while (!done);
    }
    __syncthreads();                      // release all waves into h-part
    __builtin_amdgcn_sched_barrier(0);

    // ---- h-part: 16 b128 loads, vmcnt-pipelined into 32 MFMA ----
    bf16x8 hv[16];
    const bf16_t* ap = hp + a_row * HID + s * 512 + lq * 8;
    #pragma unroll
    for (int kk = 0; kk < 16; ++kk) {
      if constexpr (COH)
        asm volatile("global_load_dwordx4 %0, %1, off offset:%2 sc0 sc1"
                     : "=v"(hv[kk]) : "v"(ap), "i"(kk * 64) : "memory");
      else
        asm volatile("global_load_dwordx4 %0, %1, off offset:%2"
                     : "=v"(hv[kk]) : "v"(ap), "i"(kk * 64) : "memory");
    }
    asm volatile("s_waitcnt vmcnt(8)" ::: "memory");
    __builtin_amdgcn_sched_barrier(0);
    #pragma unroll
    for (int kk = 0; kk < 8; ++kk) {
      int off = ((s * 16 + kk) * 64 + lq * 16) ^ nmask;
      bf16x8 b0 = *(const bf16x8*)(wr0 + off);
      bf16x8 b1 = *(const bf16x8*)(wr1 + off);
      acc0 = __builtin_amdgcn_mfma_f32_16x16x32_bf16(hv[kk], b0, acc0, 0, 0, 0);
      acc1 = __builtin_amdgcn_mfma_f32_16x16x32_bf16(hv[kk], b1, acc1, 0, 0, 0);
    }
    asm volatile("s_waitcnt vmcnt(0)" ::: "memory");
    __builtin_amdgcn_sched_barrier(0);
    #pragma unroll
    for (int kk = 8; kk < 16; ++kk) {
      int off = ((s * 16 + kk) * 64 + lq * 16) ^ nmask;
      bf16x8 b0 = *(const bf16x8*)(wr0 + off);
      bf16x8 b1 = *(const bf16x8*)(wr1 + off);
      acc0 = __builtin_amdgcn_mfma_f32_16x16x32_bf16(hv[kk], b0, acc0, 0, 0, 0);
      acc1 = __builtin_amdgcn_mfma_f32_16x16x32_bf16(hv[kk], b1, acc1, 0, 0, 0);
    }

    // ---- publish partials, sync ----
    #pragma unroll
    for (int r = 0; r < 4; ++r) {
      int brow = (w4 * 16 + lq * 4 + r) * 33;
      gb[par][s][brow + l15]      = acc0[r];
      gb[par][s][brow + 16 + l15] = acc1[r];
    }
    __syncthreads();

    // ---- wave 0: gates for its lane's batch (8 units), store, signal ----
    if (w == 0) {
      const float* g0 = &gb[par][0][lane * 33];
      const float* g1 = &gb[par][1][lane * 33];
      union { bf16_t h8[8]; u32x4 u4; } pk;
      #pragma unroll
      for (int u = 0; u < 8; ++u) {
        float gi = g0[u]      + g1[u]      + bsh[u];
        float gf = g0[8 + u]  + g1[8 + u]  + bsh[8 + u];
        float gg = g0[16 + u] + g1[16 + u] + bsh[16 + u];
        float go = g0[24 + u] + g1[24 + u] + bsh[24 + u];
        float i_ = 1.f / (1.f + __expf(-gi));
        float f_ = 1.f / (1.f + __expf(-gf));
        float g_ = 1.f - 2.f / (1.f + __expf(2.f * gg));   // tanh
        float o_ = 1.f / (1.f + __expf(-go));
        c_st[u] = f_ * c_st[u] + i_ * g_;
        pk.h8[u] = (bf16_t)(o_ * (1.f - 2.f / (1.f + __expf(2.f * c_st[u]))));
      }
      bf16_t* dst = hn + lane * HID + bb * 8;
      u32x4 val = pk.u4;
      asm volatile("global_store_dwordx4 %0, %1, off sc0 sc1"
                   :: "v"(dst), "v"(val) : "memory");
      asm volatile("s_waitcnt vmcnt(0)" ::: "memory");   // h visible at L3
      if (lane == 0)                                      // fire-and-forget add
        __hip_atomic_fetch_add(cnt + (1 + (bb >> 4)) * 1024, 1,
                               __ATOMIC_RELAXED, __HIP_MEMORY_SCOPE_AGENT);
    }
    // waves 1-7 run ahead into e-part(t+1); wave 0 rejoins at next sync
  }
}

// ---------------- final FC: out[b][j] = h[b] . fc_w[j] + fc_b[j] ----------------
__global__ __launch_bounds__(256) void k_fc(const bf16_t* __restrict__ h,
                                            const float* __restrict__ fcw,
                                            const float* __restrict__ fcb,
                                            float* __restrict__ out) {
  __shared__ float hs[HID];
  const int b = blockIdx.x >> 2, js = blockIdx.x & 3;
  const int tid = threadIdx.x;
  #pragma unroll
  for (int i = 0; i < 4; ++i) hs[tid * 4 + i] = (float)h[b * HID + tid * 4 + i];
  __syncthreads();
  int j = js * 256 + tid;
  const float4* wr = (const float4*)(fcw + (size_t)j * HID);
  float s = 0.f;
  for (int k = 0; k < 256; ++k) {
    float4 wv = wr[k];
    s += hs[k * 4] * wv.x + hs[k * 4 + 1] * wv.y + hs[k * 4 + 2] * wv.z + hs[k * 4 + 3] * wv.w;
  }
  out[b * HID + j] = s + fcb[j];
}

extern "C" void kernel_launch(void* const* d_in, const int* in_sizes, int n_in,
                              void* d_out, int out_size, void* d_ws, size_t ws_size,
                              hipStream_t stream) {
  const int*   x   = (const int*)  d_in[0];
  const float* emb = (const float*)d_in[1];
  const float* Wih = (const float*)d_in[2];
  const float* bih = (const float*)d_in[3];
  const float* Whh = (const float*)d_in[4];
  const float* bhh = (const float*)d_in[5];
  const float* fcw = (const float*)d_in[6];
  const float* fcb = (const float*)d_in[7];
  float* out = (float*)d_out;

  const size_t slot_b = (size_t)HSLOT * sizeof(bf16_t);           // 128 KB
  const size_t need_big = OFF_RING + (size_t)(T_STEPS + 1) * slot_b
                        + (size_t)MROWS * EMBD * sizeof(bf16_t);  // ~96.2 MB
  const bool big = ws_size >= need_big;
  const int  slots = big ? (T_STEPS + 1) : 2;

  char* ws = (char*)d_ws;
  int*    cnt  = (int*)   (ws + OFF_CNT);
  bf16_t* ring = (bf16_t*)(ws + OFF_RING);
  bf16_t* e_b  = (bf16_t*)(ws + OFF_RING + (size_t)slots * slot_b);
  bf16_t* hfin = ring + (size_t)(big ? T_STEPS : (T_STEPS & 1)) * HSLOT;

  // zero counters + h slot 0 every call (graph-replay safe)
  (void)hipMemsetAsync(ws, 0, OFF_RING + slot_b, stream);

  k_gather<<<MROWS / 4, 256, 0, stream>>>(x, emb, e_b);
  if (big) k_lstm<false><<<NBLK, 512, 0, stream>>>(Whh, Wih, bih, bhh, e_b, ring, cnt);
  else     k_lstm<true ><<<NBLK, 512, 0, stream>>>(Whh, Wih, bih, bhh, e_b, ring, cnt);
  k_fc<<<BATCH * 4, 256, 0, stream>>>(hfin, fcw, fcb, out);
}

// Round 7
// 3857.629 us; speedup vs baseline: 2.6691x; 1.0086x over previous
//
#include <hip/hip_runtime.h>
#include <hip/hip_bf16.h>
#include <stdint.h>

typedef __bf16 bf16_t;
typedef __bf16 bf16x8 __attribute__((ext_vector_type(8)));
typedef float  f32x4  __attribute__((ext_vector_type(4)));
typedef uint32_t u32x4 __attribute__((ext_vector_type(4)));

#define T_STEPS 512
#define BATCH   64
#define EMBD    512
#define HID     1024
#define MROWS   (T_STEPS * BATCH)   // 32768
#define HSLOT   (BATCH * HID)       // 65536 elems = 131072 B per h slot
#define NBLK    128                 // LSTM blocks; each owns 8 hidden units (32 gate rows)

// ws layout: [cnt 40KB][h ring slots*128KB][e 32MB]
#define OFF_CNT  0u
#define OFF_RING 40960u

// ---------------- embedding gather: e[t*64+b][:] = bf16(emb[x[b][t]]) ----------------
__global__ __launch_bounds__(256) void k_gather(const int* __restrict__ x,
                                                const float* __restrict__ emb,
                                                bf16_t* __restrict__ e) {
  const int row  = blockIdx.x * 4 + (threadIdx.x >> 6);  // t*64+b
  const int lane = threadIdx.x & 63;
  const int t = row >> 6, b = row & 63;
  const int id = x[b * T_STEPS + t];
  const float* src = emb + (size_t)id * EMBD + lane * 8;
  float4 a = *(const float4*)src;
  float4 c = *(const float4*)(src + 4);
  bf16x8 o;
  o[0]=(bf16_t)a.x; o[1]=(bf16_t)a.y; o[2]=(bf16_t)a.z; o[3]=(bf16_t)a.w;
  o[4]=(bf16_t)c.x; o[5]=(bf16_t)c.y; o[6]=(bf16_t)c.z; o[7]=(bf16_t)c.w;
  *(bf16x8*)(e + (size_t)row * EMBD + lane * 8) = o;
}

// ---------------- persistent LSTM scan ----------------
// 128 blocks x 512 threads. Block bb owns hidden units [bb*8,bb*8+8) = 32 gate
// rows. 8 waves = K-half s (2) x batch quarter w4 (4).
// KEY CHANGE (r7): W_hh B-fragments are loop-invariant -> pre-loaded ONCE into
// 128 VGPRs per wave (wb0/wb1[16]); per-step h-part does 32 MFMA with ZERO LDS
// reads (was 256 ds_read_b128 per block-step on the critical path). e-part
// keeps its 16 Wi LDS reads (hidden under the poll window).
// Signaling: 8 group counters on 4KB-spread lines; producer fires relaxed add
// after vmcnt(0)-drained sc0sc1 h-store; only wave 0 polls; h in write-once
// ring (normal cached loads, L2-shared per XCD) when ws permits.
template<bool COH>
__global__ __launch_bounds__(512, 1) void k_lstm(const float* __restrict__ Whh,
                                                 const float* __restrict__ Wih,
                                                 const float* __restrict__ bih,
                                                 const float* __restrict__ bhh,
                                                 const bf16_t* __restrict__ e,
                                                 bf16_t* __restrict__ ring,
                                                 int* __restrict__ cnt) {
  __shared__ __align__(16) char Ws[65536];   // [32][1024] bf16, XOR-swizzled (staging only)
  __shared__ __align__(16) char Wi[32768];   // [32][512]  bf16, XOR-swizzled
  __shared__ float gb[2][2][64 * 33];        // [parity][K-half][batch][32 gates]
  __shared__ float bsh[32];
  const int tid = threadIdx.x;
  const int lane = tid & 63;
  const int w = tid >> 6;            // 0..7
  const int s = w >> 2;              // K-half
  const int w4 = w & 3;              // batch quarter
  const int bb = blockIdx.x;
  const int l15 = lane & 15, lq = lane >> 4;
  const int nmask = (l15 & 7) << 4;

  // stage W_hh slice: 32 rows x 1024 f32 -> bf16 (4096 chunks of 8 floats)
  for (int c0 = tid; c0 < 4096; c0 += 512) {
    int n = c0 >> 7, koff = c0 & 127;
    int grow = (n >> 3) * HID + bb * 8 + (n & 7);
    const float4* src = (const float4*)(Whh + (size_t)grow * HID + koff * 8);
    float4 a = src[0], b = src[1];
    bf16x8 v;
    v[0]=(bf16_t)a.x; v[1]=(bf16_t)a.y; v[2]=(bf16_t)a.z; v[3]=(bf16_t)a.w;
    v[4]=(bf16_t)b.x; v[5]=(bf16_t)b.y; v[6]=(bf16_t)b.z; v[7]=(bf16_t)b.w;
    *(bf16x8*)(Ws + n * 2048 + ((koff * 16) ^ ((n & 7) << 4))) = v;
  }
  // stage W_ih slice: 32 rows x 512
  for (int c0 = tid; c0 < 2048; c0 += 512) {
    int n = c0 >> 6, koff = c0 & 63;
    int grow = (n >> 3) * HID + bb * 8 + (n & 7);
    const float4* src = (const float4*)(Wih + (size_t)grow * EMBD + koff * 8);
    float4 a = src[0], b = src[1];
    bf16x8 v;
    v[0]=(bf16_t)a.x; v[1]=(bf16_t)a.y; v[2]=(bf16_t)a.z; v[3]=(bf16_t)a.w;
    v[4]=(bf16_t)b.x; v[5]=(bf16_t)b.y; v[6]=(bf16_t)b.z; v[7]=(bf16_t)b.w;
    *(bf16x8*)(Wi + n * 1024 + ((koff * 16) ^ ((n & 7) << 4))) = v;
  }
  if (tid < 32) {
    int g = (tid >> 3) * HID + bb * 8 + (tid & 7);
    bsh[tid] = bih[g] + bhh[g];
  }
  __syncthreads();

  // ---- hoist loop-invariant W_hh B-fragments into VGPRs (once) ----
  const char* wr0 = Ws + l15 * 2048;            // B-tile 0 rows (gate cols 0..15)
  const char* wr1 = Ws + (16 + l15) * 2048;     // B-tile 1 rows (gate cols 16..31)
  bf16x8 wb0[16], wb1[16];
  #pragma unroll
  for (int kk = 0; kk < 16; ++kk) {
    int off = ((s * 16 + kk) * 64 + lq * 16) ^ nmask;
    wb0[kk] = *(const bf16x8*)(wr0 + off);
    wb1[kk] = *(const bf16x8*)(wr1 + off);
  }

  float c_st[8] = {0,0,0,0,0,0,0,0};   // wave-0: lane=batch, 8 hidden units
  const int a_row = w4 * 16 + l15;
  const char* wi0 = Wi + l15 * 1024;
  const char* wi1 = Wi + (16 + l15) * 1024;

  for (int t = 0; t < T_STEPS; ++t) {
    const bf16_t* hp = ring + (size_t)(COH ? (t & 1) : t) * HSLOT;
    bf16_t* hn = ring + (size_t)(COH ? ((t + 1) & 1) : (t + 1)) * HSLOT;
    const int par = t & 1;

    f32x4 acc0 = {0.f, 0.f, 0.f, 0.f};   // gate cols [0,16)
    f32x4 acc1 = {0.f, 0.f, 0.f, 0.f};   // gate cols [16,32)

    // ---- e-part (h-independent; LDS Wi reads hidden under store/signal/poll) ----
    const bf16_t* ep = e + ((size_t)t * BATCH + a_row) * EMBD + s * 256 + lq * 8;
    #pragma unroll
    for (int kk = 0; kk < 8; ++kk) {
      bf16x8 a  = *(const bf16x8*)(ep + kk * 32);
      int off = ((s * 8 + kk) * 64 + lq * 16) ^ nmask;
      bf16x8 b0 = *(const bf16x8*)(wi0 + off);
      bf16x8 b1 = *(const bf16x8*)(wi1 + off);
      acc0 = __builtin_amdgcn_mfma_f32_16x16x32_bf16(a, b0, acc0, 0, 0, 0);
      acc1 = __builtin_amdgcn_mfma_f32_16x16x32_bf16(a, b1, acc1, 0, 0, 0);
    }

    // ---- wave 0 polls the 8 group counters for step t-1 completion ----
    if (w == 0 && t > 0) {
      const int target = t * 16;
      bool done;
      do {
        int cv = (lane < 8)
          ? __hip_atomic_load(cnt + (1 + lane) * 1024, __ATOMIC_RELAXED, __HIP_MEMORY_SCOPE_AGENT)
          : 0x7fffffff;
        done = __all(cv >= target);
        if (!done) __builtin_amdgcn_s_sleep(1);
      } while (!done);
    }
    __syncthreads();                      // release all waves into h-part
    __builtin_amdgcn_sched_barrier(0);

    // ---- h-part: 16 b128 loads, vmcnt-pipelined into 32 reg-B MFMA (no LDS) ----
    bf16x8 hv[16];
    const bf16_t* ap = hp + a_row * HID + s * 512 + lq * 8;
    #pragma unroll
    for (int kk = 0; kk < 16; ++kk) {
      if constexpr (COH)
        asm volatile("global_load_dwordx4 %0, %1, off offset:%2 sc0 sc1"
                     : "=v"(hv[kk]) : "v"(ap), "i"(kk * 64) : "memory");
      else
        asm volatile("global_load_dwordx4 %0, %1, off offset:%2"
                     : "=v"(hv[kk]) : "v"(ap), "i"(kk * 64) : "memory");
    }
    asm volatile("s_waitcnt vmcnt(8)" ::: "memory");
    __builtin_amdgcn_sched_barrier(0);
    #pragma unroll
    for (int kk = 0; kk < 8; ++kk) {
      acc0 = __builtin_amdgcn_mfma_f32_16x16x32_bf16(hv[kk], wb0[kk], acc0, 0, 0, 0);
      acc1 = __builtin_amdgcn_mfma_f32_16x16x32_bf16(hv[kk], wb1[kk], acc1, 0, 0, 0);
    }
    asm volatile("s_waitcnt vmcnt(0)" ::: "memory");
    __builtin_amdgcn_sched_barrier(0);
    #pragma unroll
    for (int kk = 8; kk < 16; ++kk) {
      acc0 = __builtin_amdgcn_mfma_f32_16x16x32_bf16(hv[kk], wb0[kk], acc0, 0, 0, 0);
      acc1 = __builtin_amdgcn_mfma_f32_16x16x32_bf16(hv[kk], wb1[kk], acc1, 0, 0, 0);
    }

    // ---- publish partials, sync ----
    #pragma unroll
    for (int r = 0; r < 4; ++r) {
      int brow = (w4 * 16 + lq * 4 + r) * 33;
      gb[par][s][brow + l15]      = acc0[r];
      gb[par][s][brow + 16 + l15] = acc1[r];
    }
    __syncthreads();

    // ---- wave 0: gates for its lane's batch (8 units), store, signal ----
    if (w == 0) {
      const float* g0 = &gb[par][0][lane * 33];
      const float* g1 = &gb[par][1][lane * 33];
      union { bf16_t h8[8]; u32x4 u4; } pk;
      #pragma unroll
      for (int u = 0; u < 8; ++u) {
        float gi = g0[u]      + g1[u]      + bsh[u];
        float gf = g0[8 + u]  + g1[8 + u]  + bsh[8 + u];
        float gg = g0[16 + u] + g1[16 + u] + bsh[16 + u];
        float go = g0[24 + u] + g1[24 + u] + bsh[24 + u];
        float i_ = 1.f / (1.f + __expf(-gi));
        float f_ = 1.f / (1.f + __expf(-gf));
        float g_ = 1.f - 2.f / (1.f + __expf(2.f * gg));   // tanh
        float o_ = 1.f / (1.f + __expf(-go));
        c_st[u] = f_ * c_st[u] + i_ * g_;
        pk.h8[u] = (bf16_t)(o_ * (1.f - 2.f / (1.f + __expf(2.f * c_st[u]))));
      }
      bf16_t* dst = hn + lane * HID + bb * 8;
      u32x4 val = pk.u4;
      asm volatile("global_store_dwordx4 %0, %1, off sc0 sc1"
                   :: "v"(dst), "v"(val) : "memory");
      asm volatile("s_waitcnt vmcnt(0)" ::: "memory");   // h visible at L3
      if (lane == 0)                                      // fire-and-forget add
        __hip_atomic_fetch_add(cnt + (1 + (bb >> 4)) * 1024, 1,
                               __ATOMIC_RELAXED, __HIP_MEMORY_SCOPE_AGENT);
    }
    // waves 1-7 run ahead into e-part(t+1); wave 0 rejoins at next sync
  }
}

// ---------------- final FC: out[b][j] = h[b] . fc_w[j] + fc_b[j] ----------------
__global__ __launch_bounds__(256) void k_fc(const bf16_t* __restrict__ h,
                                            const float* __restrict__ fcw,
                                            const float* __restrict__ fcb,
                                            float* __restrict__ out) {
  __shared__ float hs[HID];
  const int b = blockIdx.x >> 2, js = blockIdx.x & 3;
  const int tid = threadIdx.x;
  #pragma unroll
  for (int i = 0; i < 4; ++i) hs[tid * 4 + i] = (float)h[b * HID + tid * 4 + i];
  __syncthreads();
  int j = js * 256 + tid;
  const float4* wr = (const float4*)(fcw + (size_t)j * HID);
  float s = 0.f;
  for (int k = 0; k < 256; ++k) {
    float4 wv = wr[k];
    s += hs[k * 4] * wv.x + hs[k * 4 + 1] * wv.y + hs[k * 4 + 2] * wv.z + hs[k * 4 + 3] * wv.w;
  }
  out[b * HID + j] = s + fcb[j];
}

extern "C" void kernel_launch(void* const* d_in, const int* in_sizes, int n_in,
                              void* d_out, int out_size, void* d_ws, size_t ws_size,
                              hipStream_t stream) {
  const int*   x   = (const int*)  d_in[0];
  const float* emb = (const float*)d_in[1];
  const float* Wih = (const float*)d_in[2];
  const float* bih = (const float*)d_in[3];
  const float* Whh = (const float*)d_in[4];
  const float* bhh = (const float*)d_in[5];
  const float* fcw = (const float*)d_in[6];
  const float* fcb = (const float*)d_in[7];
  float* out = (float*)d_out;

  const size_t slot_b = (size_t)HSLOT * sizeof(bf16_t);           // 128 KB
  const size_t need_big = OFF_RING + (size_t)(T_STEPS + 1) * slot_b
                        + (size_t)MROWS * EMBD * sizeof(bf16_t);  // ~96.2 MB
  const bool big = ws_size >= need_big;
  const int  slots = big ? (T_STEPS + 1) : 2;

  char* ws = (char*)d_ws;
  int*    cnt  = (int*)   (ws + OFF_CNT);
  bf16_t* ring = (bf16_t*)(ws + OFF_RING);
  bf16_t* e_b  = (bf16_t*)(ws + OFF_RING + (size_t)slots * slot_b);
  bf16_t* hfin = ring + (size_t)(big ? T_STEPS : (T_STEPS & 1)) * HSLOT;

  // zero counters + h slot 0 every call (graph-replay safe)
  (void)hipMemsetAsync(ws, 0, OFF_RING + slot_b, stream);

  k_gather<<<MROWS / 4, 256, 0, stream>>>(x, emb, e_b);
  if (big) k_lstm<false><<<NBLK, 512, 0, stream>>>(Whh, Wih, bih, bhh, e_b, ring, cnt);
  else     k_lstm<true ><<<NBLK, 512, 0, stream>>>(Whh, Wih, bih, bhh, e_b, ring, cnt);
  k_fc<<<BATCH * 4, 256, 0, stream>>>(hfin, fcw, fcb, out);
}

// Round 8
// 3437.212 us; speedup vs baseline: 2.9956x; 1.1223x over previous
//
#include <hip/hip_runtime.h>
#include <hip/hip_bf16.h>
#include <stdint.h>

typedef __bf16 bf16_t;
typedef __bf16 bf16x8 __attribute__((ext_vector_type(8)));
typedef float  f32x4  __attribute__((ext_vector_type(4)));
typedef uint32_t u32x4 __attribute__((ext_vector_type(4)));

#define T_STEPS 512
#define BATCH   64
#define EMBD    512
#define HID     1024
#define MROWS   (T_STEPS * BATCH)   // 32768
#define HSLOT   (BATCH * HID)       // 65536 elems = 131072 B per h slot
#define NBLK    128                 // LSTM blocks; each owns 8 hidden units
#define PITERS  128                 // probe iterations

// ws layout
#define OFF_CNT   0u                // main counters (40KB: 8 groups at 4KB spread)
#define OFF_CNT1  40960u            // P1 counters
#define OFF_CNT2  81920u            // P2 counters
#define OFF_PD    122880u           // P1 dummy ring: 2 slots * 128KB
#define OFF_PRING 385024u           // P2 ring: 2 slots * 128KB
#define OFF_RING  647168u           // main h ring: 2 slots * 128KB
#define OFF_E     (OFF_RING + 262144u)  // e bf16 [T*B][512] = 32MB

// ---------------- embedding gather: e[t*64+b][:] = bf16(emb[x[b][t]]) ----------------
__global__ __launch_bounds__(256) void k_gather(const int* __restrict__ x,
                                                const float* __restrict__ emb,
                                                bf16_t* __restrict__ e) {
  const int row  = blockIdx.x * 4 + (threadIdx.x >> 6);  // t*64+b
  const int lane = threadIdx.x & 63;
  const int t = row >> 6, b = row & 63;
  const int id = x[b * T_STEPS + t];
  const float* src = emb + (size_t)id * EMBD + lane * 8;
  float4 a = *(const float4*)src;
  float4 c = *(const float4*)(src + 4);
  bf16x8 o;
  o[0]=(bf16_t)a.x; o[1]=(bf16_t)a.y; o[2]=(bf16_t)a.z; o[3]=(bf16_t)a.w;
  o[4]=(bf16_t)c.x; o[5]=(bf16_t)c.y; o[6]=(bf16_t)c.z; o[7]=(bf16_t)c.w;
  *(bf16x8*)(e + (size_t)row * EMBD + lane * 8) = o;
}

// ---------------- persistent LSTM scan (templated: also used as ablation probes) ----
// 128 blocks x 512 threads. Block bb owns hidden units [bb*8,bb*8+8) = 32 gate rows.
// h ring layout (NEW r8): BLOCK-MAJOR — slot[blk][batch][unit]: producer stores ONE
// contiguous 1KB burst; consumer reads 256B segments. All h traffic sc0sc1.
// Gates (NEW r8): distributed — every thread owns one (batch,unit): 5 exp/lane.
// EPART=0,HPART=0 -> P1 probe: pure sync skeleton (store+drain+signal+poll+syncs).
// EPART=0,HPART=1 -> P2 probe: sync + h-load + MFMA + gates (no e-part).
template<bool EPART, bool HPART>
__global__ __launch_bounds__(512, 1) void k_lstm(const float* __restrict__ Whh,
                                                 const float* __restrict__ Wih,
                                                 const float* __restrict__ bih,
                                                 const float* __restrict__ bhh,
                                                 const bf16_t* __restrict__ e,
                                                 bf16_t* __restrict__ ring,
                                                 int* __restrict__ cnt,
                                                 int tsteps) {
  __shared__ __align__(16) char Ws[65536];   // [32][1024] bf16, XOR-swizzled (staging)
  __shared__ __align__(16) char Wi[32768];   // [32][512]  bf16, XOR-swizzled
  __shared__ float gb[2][2][64 * 33];        // [parity][K-half][batch][32 gates]
  __shared__ float bsh[32];
  __shared__ bf16_t hstage[512];             // [batch][unit] staging for 1KB store
  const int tid = threadIdx.x;
  const int lane = tid & 63;
  const int w = tid >> 6;            // 0..7
  const int s = w >> 2;              // K-half
  const int w4 = w & 3;              // batch quarter
  const int bb = blockIdx.x;
  const int l15 = lane & 15, lq = lane >> 4;
  const int nmask = (l15 & 7) << 4;

  if constexpr (HPART) {             // stage W_hh slice: 32 rows x 1024 f32->bf16
    for (int c0 = tid; c0 < 4096; c0 += 512) {
      int n = c0 >> 7, koff = c0 & 127;
      int grow = (n >> 3) * HID + bb * 8 + (n & 7);
      const float4* src = (const float4*)(Whh + (size_t)grow * HID + koff * 8);
      float4 a = src[0], b = src[1];
      bf16x8 v;
      v[0]=(bf16_t)a.x; v[1]=(bf16_t)a.y; v[2]=(bf16_t)a.z; v[3]=(bf16_t)a.w;
      v[4]=(bf16_t)b.x; v[5]=(bf16_t)b.y; v[6]=(bf16_t)b.z; v[7]=(bf16_t)b.w;
      *(bf16x8*)(Ws + n * 2048 + ((koff * 16) ^ ((n & 7) << 4))) = v;
    }
  }
  if constexpr (EPART) {             // stage W_ih slice: 32 rows x 512
    for (int c0 = tid; c0 < 2048; c0 += 512) {
      int n = c0 >> 6, koff = c0 & 63;
      int grow = (n >> 3) * HID + bb * 8 + (n & 7);
      const float4* src = (const float4*)(Wih + (size_t)grow * EMBD + koff * 8);
      float4 a = src[0], b = src[1];
      bf16x8 v;
      v[0]=(bf16_t)a.x; v[1]=(bf16_t)a.y; v[2]=(bf16_t)a.z; v[3]=(bf16_t)a.w;
      v[4]=(bf16_t)b.x; v[5]=(bf16_t)b.y; v[6]=(bf16_t)b.z; v[7]=(bf16_t)b.w;
      *(bf16x8*)(Wi + n * 1024 + ((koff * 16) ^ ((n & 7) << 4))) = v;
    }
  }
  if (tid < 32) {
    int g = (tid >> 3) * HID + bb * 8 + (tid & 7);
    bsh[tid] = bih[g] + bhh[g];
  }
  __syncthreads();

  // hoist loop-invariant W_hh B-fragments into regs (once)
  bf16x8 wb0[16], wb1[16];
  if constexpr (HPART) {
    const char* wr0 = Ws + l15 * 2048;
    const char* wr1 = Ws + (16 + l15) * 2048;
    #pragma unroll
    for (int kk = 0; kk < 16; ++kk) {
      int off = ((s * 16 + kk) * 64 + lq * 16) ^ nmask;
      wb0[kk] = *(const bf16x8*)(wr0 + off);
      wb1[kk] = *(const bf16x8*)(wr1 + off);
    }
  }

  float c_st = 0.f;                         // per-thread: one (batch,unit) cell
  const int bl = lane >> 3, un = lane & 7;  // gate-phase mapping
  const int gbatch = w * 8 + bl;
  const int a_row = w4 * 16 + l15;          // batch row for MFMA A-frags
  const char* wi0 = Wi + l15 * 1024;
  const char* wi1 = Wi + (16 + l15) * 1024;

  for (int t = 0; t < tsteps; ++t) {
    const bf16_t* hp = ring + (size_t)(t & 1) * HSLOT;
    bf16_t* hn = ring + (size_t)((t + 1) & 1) * HSLOT;
    const int par = t & 1;

    f32x4 acc0 = {0.f, 0.f, 0.f, 0.f};
    f32x4 acc1 = {0.f, 0.f, 0.f, 0.f};

    if constexpr (EPART) {   // h-independent; overlaps store/signal/poll window
      const bf16_t* ep = e + ((size_t)t * BATCH + a_row) * EMBD + s * 256 + lq * 8;
      #pragma unroll
      for (int kk = 0; kk < 8; ++kk) {
        bf16x8 a  = *(const bf16x8*)(ep + kk * 32);
        int off = ((s * 8 + kk) * 64 + lq * 16) ^ nmask;
        bf16x8 b0 = *(const bf16x8*)(wi0 + off);
        bf16x8 b1 = *(const bf16x8*)(wi1 + off);
        acc0 = __builtin_amdgcn_mfma_f32_16x16x32_bf16(a, b0, acc0, 0, 0, 0);
        acc1 = __builtin_amdgcn_mfma_f32_16x16x32_bf16(a, b1, acc1, 0, 0, 0);
      }
    }

    // wave 0 polls the 8 group counters for step t-1 completion
    if (w == 0 && t > 0) {
      const int target = t * 16;
      bool done;
      do {
        int cv = (lane < 8)
          ? __hip_atomic_load(cnt + (1 + lane) * 1024, __ATOMIC_RELAXED, __HIP_MEMORY_SCOPE_AGENT)
          : 0x7fffffff;
        done = __all(cv >= target);
        if (!done) __builtin_amdgcn_s_sleep(1);
      } while (!done);
    }
    __syncthreads();                      // release all waves into h-part
    __builtin_amdgcn_sched_barrier(0);

    if constexpr (HPART) {
      // h-part: block-major loads — blk chunk = (s*64 + kk*4 + lq), 16B at batch*8
      bf16x8 hv[16];
      const bf16_t* bp = hp + ((size_t)(s * 64 + lq) << 9) + a_row * 8;
      #pragma unroll
      for (int kk = 0; kk < 16; ++kk) {
        const bf16_t* ad = bp + kk * 2048;     // 4 chunks of 512 elems
        asm volatile("global_load_dwordx4 %0, %1, off sc0 sc1"
                     : "=v"(hv[kk]) : "v"(ad) : "memory");
      }
      asm volatile("s_waitcnt vmcnt(8)" ::: "memory");
      __builtin_amdgcn_sched_barrier(0);
      #pragma unroll
      for (int kk = 0; kk < 8; ++kk) {
        acc0 = __builtin_amdgcn_mfma_f32_16x16x32_bf16(hv[kk], wb0[kk], acc0, 0, 0, 0);
        acc1 = __builtin_amdgcn_mfma_f32_16x16x32_bf16(hv[kk], wb1[kk], acc1, 0, 0, 0);
      }
      asm volatile("s_waitcnt vmcnt(0)" ::: "memory");
      __builtin_amdgcn_sched_barrier(0);
      #pragma unroll
      for (int kk = 8; kk < 16; ++kk) {
        acc0 = __builtin_amdgcn_mfma_f32_16x16x32_bf16(hv[kk], wb0[kk], acc0, 0, 0, 0);
        acc1 = __builtin_amdgcn_mfma_f32_16x16x32_bf16(hv[kk], wb1[kk], acc1, 0, 0, 0);
      }
      #pragma unroll
      for (int r = 0; r < 4; ++r) {
        int brow = (w4 * 16 + lq * 4 + r) * 33;
        gb[par][s][brow + l15]      = acc0[r];
        gb[par][s][brow + 16 + l15] = acc1[r];
      }
    }
    __syncthreads();

    // gates: distributed — every thread does ONE (batch,unit)
    if constexpr (HPART) {
      const float* g0 = &gb[par][0][gbatch * 33];
      const float* g1 = &gb[par][1][gbatch * 33];
      float gi = g0[un]      + g1[un]      + bsh[un];
      float gf = g0[8 + un]  + g1[8 + un]  + bsh[8 + un];
      float gg = g0[16 + un] + g1[16 + un] + bsh[16 + un];
      float go = g0[24 + un] + g1[24 + un] + bsh[24 + un];
      float i_ = 1.f / (1.f + __expf(-gi));
      float f_ = 1.f / (1.f + __expf(-gf));
      float g_ = 1.f - 2.f / (1.f + __expf(2.f * gg));   // tanh
      float o_ = 1.f / (1.f + __expf(-go));
      c_st = f_ * c_st + i_ * g_;
      hstage[w * 64 + lane] = (bf16_t)(o_ * (1.f - 2.f / (1.f + __expf(2.f * c_st))));
    } else {
      hstage[w * 64 + lane] = (bf16_t)1.0f;   // P1: keep store path identical
    }
    __syncthreads();

    // wave 0: gather 1KB from hstage, ONE coalesced burst store, drain, signal
    if (w == 0) {
      u32x4 val = *(const u32x4*)(hstage + lane * 8);
      bf16_t* dst = hn + (size_t)bb * 512 + lane * 8;
      asm volatile("global_store_dwordx4 %0, %1, off sc0 sc1"
                   :: "v"(dst), "v"(val) : "memory");
      asm volatile("s_waitcnt vmcnt(0)" ::: "memory");
      if (lane == 0)
        __hip_atomic_fetch_add(cnt + (1 + (bb >> 4)) * 1024, 1,
                               __ATOMIC_RELAXED, __HIP_MEMORY_SCOPE_AGENT);
    }
    // waves 1-7 run ahead into e-part(t+1); wave 0 rejoins at next poll sync
  }
}

// ---------------- final FC: out[b][j] = h[b] . fc_w[j] + fc_b[j] ----------------
// h is block-major: h[(j>>3)*512 + b*8 + (j&7)]
__global__ __launch_bounds__(256) void k_fc(const bf16_t* __restrict__ h,
                                            const float* __restrict__ fcw,
                                            const float* __restrict__ fcb,
                                            float* __restrict__ out) {
  __shared__ float hs[HID];
  const int b = blockIdx.x >> 2, js = blockIdx.x & 3;
  const int tid = threadIdx.x;
  #pragma unroll
  for (int i = 0; i < 4; ++i) {
    int j = tid * 4 + i;
    hs[j] = (float)h[((j >> 3) << 9) + b * 8 + (j & 7)];
  }
  __syncthreads();
  int j = js * 256 + tid;
  const float4* wr = (const float4*)(fcw + (size_t)j * HID);
  float s = 0.f;
  for (int k = 0; k < 256; ++k) {
    float4 wv = wr[k];
    s += hs[k * 4] * wv.x + hs[k * 4 + 1] * wv.y + hs[k * 4 + 2] * wv.z + hs[k * 4 + 3] * wv.w;
  }
  out[b * HID + j] = s + fcb[j];
}

extern "C" void kernel_launch(void* const* d_in, const int* in_sizes, int n_in,
                              void* d_out, int out_size, void* d_ws, size_t ws_size,
                              hipStream_t stream) {
  const int*   x   = (const int*)  d_in[0];
  const float* emb = (const float*)d_in[1];
  const float* Wih = (const float*)d_in[2];
  const float* bih = (const float*)d_in[3];
  const float* Whh = (const float*)d_in[4];
  const float* bhh = (const float*)d_in[5];
  const float* fcw = (const float*)d_in[6];
  const float* fcb = (const float*)d_in[7];
  float* out = (float*)d_out;

  char* ws = (char*)d_ws;
  int*    cnt   = (int*)   (ws + OFF_CNT);
  int*    cnt1  = (int*)   (ws + OFF_CNT1);
  int*    cnt2  = (int*)   (ws + OFF_CNT2);
  bf16_t* pd    = (bf16_t*)(ws + OFF_PD);
  bf16_t* pring = (bf16_t*)(ws + OFF_PRING);
  bf16_t* ring  = (bf16_t*)(ws + OFF_RING);
  bf16_t* e_b   = (bf16_t*)(ws + OFF_E);
  bf16_t* hfin  = ring;   // T_STEPS even -> final h in slot 0

  // zero all counters + probe rings + main slot 0 (graph-replay safe)
  (void)hipMemsetAsync(ws, 0, OFF_RING + (size_t)HSLOT * sizeof(bf16_t), stream);

  k_gather<<<MROWS / 4, 256, 0, stream>>>(x, emb, e_b);
  k_lstm<true, true><<<NBLK, 512, 0, stream>>>(Whh, Wih, bih, bhh, e_b, ring, cnt, T_STEPS);
  k_fc<<<BATCH * 4, 256, 0, stream>>>(hfin, fcw, fcb, out);

  // ---- ablation probes (rocprof-visible; removed once read) ----
  k_lstm<false, false><<<NBLK, 512, 0, stream>>>(Whh, Wih, bih, bhh, e_b, pd, cnt1, PITERS);
  k_lstm<false, true ><<<NBLK, 512, 0, stream>>>(Whh, Wih, bih, bhh, e_b, pring, cnt2, PITERS);
}

// Round 9
// 3055.801 us; speedup vs baseline: 3.3695x; 1.1248x over previous
//
#include <hip/hip_runtime.h>
#include <hip/hip_bf16.h>
#include <stdint.h>

typedef __bf16 bf16_t;
typedef __bf16 bf16x8 __attribute__((ext_vector_type(8)));
typedef float  f32x4  __attribute__((ext_vector_type(4)));
typedef uint32_t u32x4 __attribute__((ext_vector_type(4)));

#define T_STEPS 512
#define BATCH   64
#define EMBD    512
#define HID     1024
#define MROWS   (T_STEPS * BATCH)   // 32768
#define HSLOT   (BATCH * HID)       // 65536 elems = 131072 B per h slot
#define NBLK    128                 // LSTM blocks; each owns 8 hidden units

// ws layout
#define OFF_FLAGS 0u                    // 128 flags, 256B apart = 32KB
#define OFF_RING  32768u                // h ring: 2 slots * 128KB
#define OFF_E     (OFF_RING + 262144u)  // e bf16 [T*B][512] = 32MB

// ---------------- embedding gather: e[t*64+b][:] = bf16(emb[x[b][t]]) ----------------
__global__ __launch_bounds__(256) void k_gather(const int* __restrict__ x,
                                                const float* __restrict__ emb,
                                                bf16_t* __restrict__ e) {
  const int row  = blockIdx.x * 4 + (threadIdx.x >> 6);  // t*64+b
  const int lane = threadIdx.x & 63;
  const int t = row >> 6, b = row & 63;
  const int id = x[b * T_STEPS + t];
  const float* src = emb + (size_t)id * EMBD + lane * 8;
  float4 a = *(const float4*)src;
  float4 c = *(const float4*)(src + 4);
  bf16x8 o;
  o[0]=(bf16_t)a.x; o[1]=(bf16_t)a.y; o[2]=(bf16_t)a.z; o[3]=(bf16_t)a.w;
  o[4]=(bf16_t)c.x; o[5]=(bf16_t)c.y; o[6]=(bf16_t)c.z; o[7]=(bf16_t)c.w;
  *(bf16x8*)(e + (size_t)row * EMBD + lane * 8) = o;
}

// ---------------- persistent LSTM scan ----------------
// 128 blocks x 512 threads. Block bb owns hidden units [bb*8,bb*8+8) = 32 gate rows.
// h ring: block-major [blk][batch][unit]; producer = wave 0, ONE 1KB burst store
// (sc0sc1) + vmcnt(0) drain + plain flag store (t+1) to its own 256B line — NO
// atomic fan-in. Signal consumption (r9): wave 1 polls the 8 flag-groups (16
// lanes each) and publishes LDS ready[g]; compute waves spin on LDS per group
// and pipeline: spin(g) -> 4 h-loads(g) -> MFMA(g-1), overlapping loads/compute
// with still-late producers. Gates distributed (1 per thread). gb parity-
// buffered so waves run ahead one step across barriers.
__global__ __launch_bounds__(512, 1) void k_lstm(const float* __restrict__ Whh,
                                                 const float* __restrict__ Wih,
                                                 const float* __restrict__ bih,
                                                 const float* __restrict__ bhh,
                                                 const bf16_t* __restrict__ e,
                                                 bf16_t* __restrict__ ring,
                                                 int* __restrict__ flags) {
  __shared__ __align__(16) char Ws[65536];   // [32][1024] bf16, XOR-swizzled (staging)
  __shared__ __align__(16) char Wi[32768];   // [32][512]  bf16, XOR-swizzled
  __shared__ float gb[2][2][64 * 33];        // [parity][K-half][batch][32 gates]
  __shared__ float bsh[32];
  __shared__ bf16_t hstage[512];             // [batch][unit]
  __shared__ int ready[8];                   // per-group LDS tokens (monotone = t)
  const int tid = threadIdx.x;
  const int lane = tid & 63;
  const int w = tid >> 6;            // 0..7
  const int s = w >> 2;              // K-half
  const int w4 = w & 3;              // batch quarter
  const int bb = blockIdx.x;
  const int l15 = lane & 15, lq = lane >> 4;
  const int nmask = (l15 & 7) << 4;

  // stage W_hh slice: 32 rows x 1024 f32->bf16, swizzled
  for (int c0 = tid; c0 < 4096; c0 += 512) {
    int n = c0 >> 7, koff = c0 & 127;
    int grow = (n >> 3) * HID + bb * 8 + (n & 7);
    const float4* src = (const float4*)(Whh + (size_t)grow * HID + koff * 8);
    float4 a = src[0], b = src[1];
    bf16x8 v;
    v[0]=(bf16_t)a.x; v[1]=(bf16_t)a.y; v[2]=(bf16_t)a.z; v[3]=(bf16_t)a.w;
    v[4]=(bf16_t)b.x; v[5]=(bf16_t)b.y; v[6]=(bf16_t)b.z; v[7]=(bf16_t)b.w;
    *(bf16x8*)(Ws + n * 2048 + ((koff * 16) ^ ((n & 7) << 4))) = v;
  }
  // stage W_ih slice: 32 rows x 512
  for (int c0 = tid; c0 < 2048; c0 += 512) {
    int n = c0 >> 6, koff = c0 & 63;
    int grow = (n >> 3) * HID + bb * 8 + (n & 7);
    const float4* src = (const float4*)(Wih + (size_t)grow * EMBD + koff * 8);
    float4 a = src[0], b = src[1];
    bf16x8 v;
    v[0]=(bf16_t)a.x; v[1]=(bf16_t)a.y; v[2]=(bf16_t)a.z; v[3]=(bf16_t)a.w;
    v[4]=(bf16_t)b.x; v[5]=(bf16_t)b.y; v[6]=(bf16_t)b.z; v[7]=(bf16_t)b.w;
    *(bf16x8*)(Wi + n * 1024 + ((koff * 16) ^ ((n & 7) << 4))) = v;
  }
  if (tid < 32) {
    int g = (tid >> 3) * HID + bb * 8 + (tid & 7);
    bsh[tid] = bih[g] + bhh[g];
  }
  if (tid < 8) ready[tid] = 0;
  __syncthreads();

  // hoist loop-invariant W_hh B-fragments into regs
  bf16x8 wb0[16], wb1[16];
  {
    const char* wr0 = Ws + l15 * 2048;
    const char* wr1 = Ws + (16 + l15) * 2048;
    #pragma unroll
    for (int kk = 0; kk < 16; ++kk) {
      int off = ((s * 16 + kk) * 64 + lq * 16) ^ nmask;
      wb0[kk] = *(const bf16x8*)(wr0 + off);
      wb1[kk] = *(const bf16x8*)(wr1 + off);
    }
  }

  float c_st = 0.f;                         // per-thread (batch,unit) cell state
  const int un = lane & 7;
  const int gbatch = w * 8 + (lane >> 3);
  const int a_row = w4 * 16 + l15;          // batch row for MFMA A-frags
  const char* wi0 = Wi + l15 * 1024;
  const char* wi1 = Wi + (16 + l15) * 1024;

  for (int t = 0; t < T_STEPS; ++t) {
    const bf16_t* hp = ring + (size_t)(t & 1) * HSLOT;
    bf16_t* hn = ring + (size_t)((t + 1) & 1) * HSLOT;
    const int par = t & 1;

    f32x4 acc0 = {0.f, 0.f, 0.f, 0.f};
    f32x4 acc1 = {0.f, 0.f, 0.f, 0.f};

    // ---- e-part (h-independent; overlaps producer/flag latency) ----
    {
      const bf16_t* ep = e + ((size_t)t * BATCH + a_row) * EMBD + s * 256 + lq * 8;
      #pragma unroll
      for (int kk = 0; kk < 8; ++kk) {
        bf16x8 a  = *(const bf16x8*)(ep + kk * 32);
        int off = ((s * 8 + kk) * 64 + lq * 16) ^ nmask;
        bf16x8 b0 = *(const bf16x8*)(wi0 + off);
        bf16x8 b1 = *(const bf16x8*)(wi1 + off);
        acc0 = __builtin_amdgcn_mfma_f32_16x16x32_bf16(a, b0, acc0, 0, 0, 0);
        acc1 = __builtin_amdgcn_mfma_f32_16x16x32_bf16(a, b1, acc1, 0, 0, 0);
      }
    }

    // ---- wave 1: poll flag groups, publish LDS ready tokens ----
    if (w == 1 && t > 0) {
      for (int g = 0; g < 8; ++g) {
        bool done;
        do {
          int cv = (lane < 16)
            ? __hip_atomic_load(flags + (g * 16 + lane) * 64, __ATOMIC_RELAXED, __HIP_MEMORY_SCOPE_AGENT)
            : 0x7fffffff;
          done = __all(cv >= t);
          if (!done) __builtin_amdgcn_s_sleep(1);
        } while (!done);
        __hip_atomic_store(&ready[g], t, __ATOMIC_RELEASE, __HIP_MEMORY_SCOPE_WORKGROUP);
      }
    }

    // ---- h-part: per-group {LDS spin -> 4 loads}, software-pipelined MFMA ----
    bf16x8 hv[16];
    const bf16_t* bp = hp + ((size_t)(s * 64 + lq) << 9) + a_row * 8;
    #define SPIN(g)                                                                   \
      if (t > 0) {                                                                    \
        while (__hip_atomic_load(&ready[s * 4 + (g)], __ATOMIC_ACQUIRE,               \
                                 __HIP_MEMORY_SCOPE_WORKGROUP) < t)                   \
          __builtin_amdgcn_s_sleep(1);                                                \
      }                                                                               \
      __builtin_amdgcn_sched_barrier(0);
    #define LOAD4(j)                                                                  \
      _Pragma("unroll")                                                               \
      for (int m = 0; m < 4; ++m) {                                                   \
        const bf16_t* ad = bp + ((j) * 4 + m) * 2048;                                 \
        asm volatile("global_load_dwordx4 %0, %1, off sc0 sc1"                        \
                     : "=v"(hv[(j) * 4 + m]) : "v"(ad) : "memory");                   \
      }
    #define MFMA4(j)                                                                  \
      _Pragma("unroll")                                                               \
      for (int m = 0; m < 4; ++m) {                                                   \
        int kk = (j) * 4 + m;                                                         \
        acc0 = __builtin_amdgcn_mfma_f32_16x16x32_bf16(hv[kk], wb0[kk], acc0, 0, 0, 0); \
        acc1 = __builtin_amdgcn_mfma_f32_16x16x32_bf16(hv[kk], wb1[kk], acc1, 0, 0, 0); \
      }
    SPIN(0) LOAD4(0)
    SPIN(1) LOAD4(1)
    asm volatile("s_waitcnt vmcnt(4)" ::: "memory");
    __builtin_amdgcn_sched_barrier(0);
    MFMA4(0)
    SPIN(2) LOAD4(2)
    asm volatile("s_waitcnt vmcnt(4)" ::: "memory");
    __builtin_amdgcn_sched_barrier(0);
    MFMA4(1)
    SPIN(3) LOAD4(3)
    asm volatile("s_waitcnt vmcnt(4)" ::: "memory");
    __builtin_amdgcn_sched_barrier(0);
    MFMA4(2)
    asm volatile("s_waitcnt vmcnt(0)" ::: "memory");
    __builtin_amdgcn_sched_barrier(0);
    MFMA4(3)
    #undef SPIN
    #undef LOAD4
    #undef MFMA4

    // ---- publish partials, sync ----
    #pragma unroll
    for (int r = 0; r < 4; ++r) {
      int brow = (w4 * 16 + lq * 4 + r) * 33;
      gb[par][s][brow + l15]      = acc0[r];
      gb[par][s][brow + 16 + l15] = acc1[r];
    }
    __syncthreads();

    // ---- gates: distributed, one (batch,unit) per thread ----
    {
      const float* g0 = &gb[par][0][gbatch * 33];
      const float* g1 = &gb[par][1][gbatch * 33];
      float gi = g0[un]      + g1[un]      + bsh[un];
      float gf = g0[8 + un]  + g1[8 + un]  + bsh[8 + un];
      float gg = g0[16 + un] + g1[16 + un] + bsh[16 + un];
      float go = g0[24 + un] + g1[24 + un] + bsh[24 + un];
      float i_ = 1.f / (1.f + __expf(-gi));
      float f_ = 1.f / (1.f + __expf(-gf));
      float g_ = 1.f - 2.f / (1.f + __expf(2.f * gg));   // tanh
      float o_ = 1.f / (1.f + __expf(-go));
      c_st = f_ * c_st + i_ * g_;
      hstage[tid] = (bf16_t)(o_ * (1.f - 2.f / (1.f + __expf(2.f * c_st))));
    }
    __syncthreads();

    // ---- wave 0: gather 1KB, ONE burst store, drain, flag store ----
    if (w == 0) {
      u32x4 val = *(const u32x4*)(hstage + lane * 8);
      bf16_t* dst = hn + (size_t)bb * 512 + lane * 8;
      asm volatile("global_store_dwordx4 %0, %1, off sc0 sc1"
                   :: "v"(dst), "v"(val) : "memory");
      asm volatile("s_waitcnt vmcnt(0)" ::: "memory");   // h visible at L3
      if (lane == 0)
        __hip_atomic_store(flags + bb * 64, t + 1,
                           __ATOMIC_RELAXED, __HIP_MEMORY_SCOPE_AGENT);
    }
    // waves run ahead into e-part(t+1); parity gb + monotone tokens keep it safe
  }
}

// ---------------- final FC: out[b][j] = h[b] . fc_w[j] + fc_b[j] ----------------
// h is block-major: h[(j>>3)*512 + b*8 + (j&7)]
__global__ __launch_bounds__(256) void k_fc(const bf16_t* __restrict__ h,
                                            const float* __restrict__ fcw,
                                            const float* __restrict__ fcb,
                                            float* __restrict__ out) {
  __shared__ float hs[HID];
  const int b = blockIdx.x >> 2, js = blockIdx.x & 3;
  const int tid = threadIdx.x;
  #pragma unroll
  for (int i = 0; i < 4; ++i) {
    int j = tid * 4 + i;
    hs[j] = (float)h[((j >> 3) << 9) + b * 8 + (j & 7)];
  }
  __syncthreads();
  int j = js * 256 + tid;
  const float4* wr = (const float4*)(fcw + (size_t)j * HID);
  float s = 0.f;
  for (int k = 0; k < 256; ++k) {
    float4 wv = wr[k];
    s += hs[k * 4] * wv.x + hs[k * 4 + 1] * wv.y + hs[k * 4 + 2] * wv.z + hs[k * 4 + 3] * wv.w;
  }
  out[b * HID + j] = s + fcb[j];
}

extern "C" void kernel_launch(void* const* d_in, const int* in_sizes, int n_in,
                              void* d_out, int out_size, void* d_ws, size_t ws_size,
                              hipStream_t stream) {
  const int*   x   = (const int*)  d_in[0];
  const float* emb = (const float*)d_in[1];
  const float* Wih = (const float*)d_in[2];
  const float* bih = (const float*)d_in[3];
  const float* Whh = (const float*)d_in[4];
  const float* bhh = (const float*)d_in[5];
  const float* fcw = (const float*)d_in[6];
  const float* fcb = (const float*)d_in[7];
  float* out = (float*)d_out;

  char* ws = (char*)d_ws;
  int*    flags = (int*)   (ws + OFF_FLAGS);
  bf16_t* ring  = (bf16_t*)(ws + OFF_RING);
  bf16_t* e_b   = (bf16_t*)(ws + OFF_E);
  bf16_t* hfin  = ring;   // T_STEPS even -> final h in slot 0

  // zero flags + h slot 0 every call (graph-replay safe)
  (void)hipMemsetAsync(ws, 0, OFF_RING + (size_t)HSLOT * sizeof(bf16_t), stream);

  k_gather<<<MROWS / 4, 256, 0, stream>>>(x, emb, e_b);
  k_lstm<<<NBLK, 512, 0, stream>>>(Whh, Wih, bih, bhh, e_b, ring, flags);
  k_fc<<<BATCH * 4, 256, 0, stream>>>(hfin, fcw, fcb, out);
}